// Round 13
// baseline (503.617 us; speedup 1.0000x reference)
//
#include <hip/hip_runtime.h>
#include <math.h>

#define N_ATOMS   50000
#define N_PAD     50048          // padded row count (multiple of 64)
#define N_EDGES   600000
#define N_FEAT    128
#define N_GAUSS   32
#define N_CONV    3
#define N_MOLS    1000
#define HIDDEN_RO 64
#define CAP       64             // incidence bucket capacity (mean deg 24, max ~47)

#define TBL_N     7681           // table rows per layer, d = i/1024, covers [0, 7.5]
#define TBL_BPL   121
#define TBL_SCALE 1024.0f
#define TBL_TMAX  7679.0f
#define NB_EDGE   2344           // 293 chunks x 8 classes
#define NB_BUILD  (N_CONV * TBL_BPL)   // 363
#define NB_EMBG   7
#define NB_WPREP  40

typedef unsigned int   uint32;
typedef unsigned short u16;
typedef __attribute__((ext_vector_type(8))) short bf16x8;
typedef __attribute__((ext_vector_type(4))) float f32x4;

__device__ __forceinline__ float ssp_f(float x) {
    float e = __expf(-fabsf(x));
    return fmaxf(x, 0.0f) + __logf(1.0f + e) - 0.6931471805599453f;
}
__device__ __forceinline__ uint32 f2bf_u(float x) {
    uint32 u = __float_as_uint(x);
    return (u + 0x7fffu + ((u >> 16) & 1u)) >> 16;
}
__device__ __forceinline__ uint32 pack2f(float a, float b) {
    return f2bf_u(a) | (f2bf_u(b) << 16);
}
__device__ __forceinline__ float bf_lo(uint32 u) { return __uint_as_float(u << 16); }
__device__ __forceinline__ float bf_hi(uint32 u) { return __uint_as_float(u & 0xffff0000u); }

// ================= uber-A: build | embG | wprep | XCD-classed dist+fill =================
#define FILL_START (NB_BUILD + NB_EMBG + NB_WPREP)   // 410
__global__ __launch_bounds__(256)
void k_uberA(const int* __restrict__ nbr, const float* __restrict__ xyz,
             int* __restrict__ cnt, uint32* __restrict__ inc32,
             const float* __restrict__ We1_all, const float* __restrict__ be1_all,
             const float* __restrict__ We2_all, const float* __restrict__ be2_all,
             uint32* __restrict__ tblI,
             const float* __restrict__ Wn, const float* __restrict__ bn,
             const float* __restrict__ Wu1,
             const float* __restrict__ Wu2, const float* __restrict__ Wr1,
             u16* __restrict__ Wt, const float* __restrict__ embed,
             float* __restrict__ Gp) {
    __shared__ float smemA[26112 / 4];
    int b = blockIdx.x;
    int t = threadIdx.x;

    if (b < NB_BUILD) {
        int l    = b / TBL_BPL;
        int row0 = (b % TBL_BPL) * 64;
        const float* We1 = We1_all + (size_t)l * N_GAUSS * N_FEAT;
        const float* be1 = be1_all + (size_t)l * N_FEAT;
        const float* We2 = We2_all + (size_t)l * N_FEAT * N_FEAT;
        const float* be2 = be2_all + (size_t)l * N_FEAT;
        uint32* tl = tblI + (size_t)l * TBL_N * 128;
        float (*gT)[68] = (float(*)[68])smemA;
        u16* h1T = (u16*)(smemA + 32 * 68);

        const float width = 5.0f / 31.0f;
        const float coef = -0.5f / (width * width);
        #pragma unroll
        for (int i = 0; i < 8; ++i) {
            int idx = t + 256 * i;
            int g = idx >> 6, e = idx & 63;
            float d = (float)(row0 + e) * (1.0f / TBL_SCALE);
            float diff = d - (float)g * width;
            gT[g][e] = __expf(coef * diff * diff);
        }
        __syncthreads();

        int tf = t & 15, te = t >> 4;
        int f0 = tf * 8, eb = te * 4;
        float acc[4][8];
        #pragma unroll
        for (int i = 0; i < 4; ++i)
            #pragma unroll
            for (int j = 0; j < 8; ++j) acc[i][j] = 0.0f;

        #pragma unroll 4
        for (int g = 0; g < N_GAUSS; ++g) {
            float4 a  = *(const float4*)&gT[g][eb];
            float4 w0 = *(const float4*)(We1 + g * N_FEAT + f0);
            float4 w1 = *(const float4*)(We1 + g * N_FEAT + f0 + 4);
            float av[4] = {a.x, a.y, a.z, a.w};
            float wv[8] = {w0.x, w0.y, w0.z, w0.w, w1.x, w1.y, w1.z, w1.w};
            #pragma unroll
            for (int i = 0; i < 4; ++i)
                #pragma unroll
                for (int j = 0; j < 8; ++j) acc[i][j] += av[i] * wv[j];
        }
        #pragma unroll
        for (int j = 0; j < 8; ++j) {
            float bb2 = be1[f0 + j];
            uint2 hv;
            hv.x = pack2f(ssp_f(acc[0][j] + bb2), ssp_f(acc[1][j] + bb2));
            hv.y = pack2f(ssp_f(acc[2][j] + bb2), ssp_f(acc[3][j] + bb2));
            *(uint2*)&h1T[(f0 + j) * 68 + eb] = hv;
        }
        __syncthreads();

        #pragma unroll
        for (int i = 0; i < 4; ++i)
            #pragma unroll
            for (int j = 0; j < 8; ++j) acc[i][j] = 0.0f;
        #pragma unroll 2
        for (int c = 0; c < N_FEAT; ++c) {
            uint2 hv = *(const uint2*)&h1T[c * 68 + eb];
            float av[4] = {bf_lo(hv.x), bf_hi(hv.x), bf_lo(hv.y), bf_hi(hv.y)};
            float4 w0 = *(const float4*)(We2 + c * N_FEAT + f0);
            float4 w1 = *(const float4*)(We2 + c * N_FEAT + f0 + 4);
            float wv[8] = {w0.x, w0.y, w0.z, w0.w, w1.x, w1.y, w1.z, w1.w};
            #pragma unroll
            for (int i = 0; i < 4; ++i)
                #pragma unroll
                for (int j = 0; j < 8; ++j) acc[i][j] += av[i] * wv[j];
        }
        __syncthreads();

        uint32* pvS = (uint32*)smemA;   // [64][65]
        #pragma unroll
        for (int i = 0; i < 4; ++i)
            #pragma unroll
            for (int p = 0; p < 4; ++p)
                pvS[(eb + i) * 65 + tf * 4 + p] =
                    pack2f(acc[i][2 * p]     + be2[f0 + 2 * p],
                           acc[i][2 * p + 1] + be2[f0 + 2 * p + 1]);
        __syncthreads();

        #pragma unroll
        for (int i = 0; i < 16; ++i) {
            int idx = t + 256 * i;
            int e = idx >> 6, fp = idx & 63;
            int ent = row0 + e;
            if (ent < TBL_N - 1) {
                if (e < 63) {
                    uint2 v2;
                    v2.x = pvS[e * 65 + fp];
                    v2.y = pvS[(e + 1) * 65 + fp];
                    *(uint2*)(tl + ((size_t)ent * 64 + fp) * 2) = v2;
                } else {
                    tl[((size_t)ent * 64 + fp) * 2] = pvS[63 * 65 + fp];
                }
            }
        }
        if (row0 > 0 && t < 64)
            tl[((size_t)(row0 - 1) * 64 + t) * 2 + 1] = pvS[t];
        return;
    }
    if (b < NB_BUILD + NB_EMBG) {
        int bb = b - NB_BUILD;
        int row = bb * 16 + (t >> 4);
        int tf = t & 15;
        if (row < 100) {
            float acc[8];
            #pragma unroll
            for (int j = 0; j < 8; ++j) acc[j] = 0.0f;
            for (int k = 0; k < N_FEAT; ++k) {
                float a = embed[row * N_FEAT + k];
                float4 w0 = *(const float4*)(Wn + k * N_FEAT + tf * 8);
                float4 w1 = *(const float4*)(Wn + k * N_FEAT + tf * 8 + 4);
                acc[0] += a * w0.x; acc[1] += a * w0.y;
                acc[2] += a * w0.z; acc[3] += a * w0.w;
                acc[4] += a * w1.x; acc[5] += a * w1.y;
                acc[6] += a * w1.z; acc[7] += a * w1.w;
            }
            #pragma unroll
            for (int j = 0; j < 8; ++j)
                Gp[row * N_FEAT + tf * 8 + j] = acc[j] + bn[tf * 8 + j];
        }
        return;
    }
    if (b < FILL_START) {
        int wb = b - NB_BUILD - NB_EMBG;
        int gid = wb * 256 + t;
        #pragma unroll
        for (int i = 0; i < 16; ++i) {
            int idx = gid + i * (NB_WPREP * 256);
            int mat = idx >> 14;
            int e = idx & 16383;
            int n = e >> 7, k = e & 127;
            float v;
            if (mat < 3)      v = Wn [(size_t)mat * 16384 + k * 128 + n];
            else if (mat < 6) v = Wu1[(size_t)(mat - 3) * 16384 + k * 128 + n];
            else if (mat < 9) v = Wu2[(size_t)(mat - 6) * 16384 + k * 128 + n];
            else { int key = n >> 6, h = n & 63; v = Wr1[(size_t)key * 128 * 64 + k * 64 + h]; }
            Wt[(size_t)mat * 16384 + n * 128 + k] = (u16)f2bf_u(v);
        }
        return;
    }
    // ---- dist + fill, XCD-class partitioned ----
    {
        int cls = b & 7;
        int base = ((b - FILL_START) >> 3) * 2048;
        #pragma unroll
        for (int i = 0; i < 8; ++i) {
            int e = base + t + 256 * i;
            if (e < N_EDGES) {
                int a0 = nbr[2 * e], a1 = nbr[2 * e + 1];
                bool m0 = (a0 & 7) == cls, m1 = (a1 & 7) == cls;
                if (m0 | m1) {
                    float dx = xyz[3 * a0]     - xyz[3 * a1];
                    float dy = xyz[3 * a0 + 1] - xyz[3 * a1 + 1];
                    float dz = xyz[3 * a0 + 2] - xyz[3 * a1 + 2];
                    float d = sqrtf(dx * dx + dy * dy + dz * dz);
                    float tv = fminf(d * TBL_SCALE, TBL_TMAX);
                    uint32 tq = (uint32)(tv * 8.0f + 0.5f);
                    if (m1) {
                        int p1 = atomicAdd(&cnt[a1], 1);
                        if (p1 < CAP) inc32[((size_t)a1 << 6) | p1] = ((uint32)a0 << 16) | tq;
                    }
                    if (m0) {
                        int p0 = atomicAdd(&cnt[a0], 1);
                        if (p0 < CAP) inc32[((size_t)a0 << 6) | p0] = ((uint32)a1 << 16) | tq;
                    }
                }
            }
        }
    }
}

// ================= gather: r = embed[z], rf16 = bf16(G'[z]) =================
__global__ __launch_bounds__(256)
void k_gather(const int* __restrict__ z, const float* __restrict__ embed,
              const float* __restrict__ Gp, float* __restrict__ r,
              uint32* __restrict__ rf16) {
    int idx = blockIdx.x * 256 + threadIdx.x;
    if (idx >= N_PAD * 32) return;
    int n = idx >> 5, c4 = idx & 31;
    int zz = z[n < N_ATOMS ? n : 0];
    float4 v = *(const float4*)(embed + (size_t)zz * N_FEAT + c4 * 4);
    *(float4*)(r + (size_t)n * N_FEAT + c4 * 4) = v;
    float4 g = *(const float4*)(Gp + (size_t)zz * N_FEAT + c4 * 4);
    uint2 o;
    o.x = pack2f(g.x, g.y);
    o.y = pack2f(g.z, g.w);
    *(uint2*)(rf16 + (size_t)n * 64 + c4 * 2) = o;
}

// ================= fused layer: agg (LDS) + 3-GEMM chain, 32-atom tiles =================
// rf_in (read globally, prev layer) and rf_out (written, next layer) are DIFFERENT buffers.
template <bool RO>
__global__ __launch_bounds__(256)
void k_layer(const int* __restrict__ cnt, const uint32* __restrict__ inc32,
             const uint32* __restrict__ tblI, const uint32* __restrict__ rf_in,
             const float* __restrict__ bu1, const float* __restrict__ bu2,
             const u16* __restrict__ Wu1t, const u16* __restrict__ Wu2t,
             const u16* __restrict__ W3t, const float* __restrict__ b3,
             float* __restrict__ r, u16* __restrict__ rf_out,
             const float* __restrict__ Wr2, const float* __restrict__ br2,
             const int* __restrict__ mol, float* __restrict__ out) {
    __shared__ u16 aT[32 * 136];   // 8704 B; re-used as red[32][4][17] in RO epilogue
    __shared__ u16 hT[32 * 136];

    int tid = threadIdx.x;
    int w = tid >> 6, lane = tid & 63;
    int l15 = lane & 15, q = lane >> 4;
    int colbase = w * 32;
    size_t n0 = (size_t)blockIdx.x * 32;

    // ---- phase 1: aggregation for this block's 32 atoms (wave w -> rows w*8..w*8+7) ----
    {
        int h = lane >> 5, lh = lane & 31;
        for (int ai = 0; ai < 8; ++ai) {
            int row = w * 8 + ai;
            int n = (int)n0 + row;
            float a0 = 0.f, a1 = 0.f, a2 = 0.f, a3 = 0.f;
            if (n < N_ATOMS) {
                int s = n << 6;
                int e = s + min(cnt[n], CAP);
                int i = s;
                for (; i + 8 <= e; i += 8) {
                    uint32 v[4];
                    #pragma unroll
                    for (int u = 0; u < 4; ++u) v[u] = inc32[i + 2 * u + h];
                    int i0[4], oa[4];
                    float fr[4];
                    #pragma unroll
                    for (int u = 0; u < 4; ++u) {
                        oa[u] = v[u] >> 16;
                        uint32 tq = v[u] & 0xffffu;
                        i0[u] = tq >> 3;
                        fr[u] = (float)(tq & 7u) * 0.125f;
                    }
                    uint4 T[4];
                    #pragma unroll
                    for (int u = 0; u < 4; ++u) T[u] = *(const uint4*)(tblI + ((size_t)i0[u] * 64 + lh * 2) * 2);
                    uint2 R[4];
                    #pragma unroll
                    for (int u = 0; u < 4; ++u) R[u] = *(const uint2*)(rf_in + (size_t)oa[u] * 64 + lh * 2);
                    #pragma unroll
                    for (int u = 0; u < 4; ++u) {
                        float e0 = fmaf(fr[u], bf_lo(T[u].y) - bf_lo(T[u].x), bf_lo(T[u].x));
                        float e1 = fmaf(fr[u], bf_hi(T[u].y) - bf_hi(T[u].x), bf_hi(T[u].x));
                        float e2 = fmaf(fr[u], bf_lo(T[u].w) - bf_lo(T[u].z), bf_lo(T[u].z));
                        float e3 = fmaf(fr[u], bf_hi(T[u].w) - bf_hi(T[u].z), bf_hi(T[u].z));
                        a0 = fmaf(e0, bf_lo(R[u].x), a0);
                        a1 = fmaf(e1, bf_hi(R[u].x), a1);
                        a2 = fmaf(e2, bf_lo(R[u].y), a2);
                        a3 = fmaf(e3, bf_hi(R[u].y), a3);
                    }
                }
                for (; i < e; i += 2) {
                    int idx = i + h;
                    bool ok = idx < e;
                    uint32 v = inc32[ok ? idx : s];
                    int oa = v >> 16;
                    uint32 tq = v & 0xffffu;
                    int i0 = tq >> 3;
                    float fr = (float)(tq & 7u) * 0.125f;
                    uint4 T = *(const uint4*)(tblI + ((size_t)i0 * 64 + lh * 2) * 2);
                    uint2 R = *(const uint2*)(rf_in + (size_t)oa * 64 + lh * 2);
                    float m = ok ? 1.0f : 0.0f;
                    float e0 = fmaf(fr, bf_lo(T.y) - bf_lo(T.x), bf_lo(T.x));
                    float e1 = fmaf(fr, bf_hi(T.y) - bf_hi(T.x), bf_hi(T.x));
                    float e2 = fmaf(fr, bf_lo(T.w) - bf_lo(T.z), bf_lo(T.z));
                    float e3 = fmaf(fr, bf_hi(T.w) - bf_hi(T.z), bf_hi(T.z));
                    a0 = fmaf(e0, m * bf_lo(R.x), a0);
                    a1 = fmaf(e1, m * bf_hi(R.x), a1);
                    a2 = fmaf(e2, m * bf_lo(R.y), a2);
                    a3 = fmaf(e3, m * bf_hi(R.y), a3);
                }
                a0 += __shfl_xor(a0, 32);
                a1 += __shfl_xor(a1, 32);
                a2 += __shfl_xor(a2, 32);
                a3 += __shfl_xor(a3, 32);
            }
            if (h == 0) {
                uint2 o;
                o.x = pack2f(a0, a1);
                o.y = pack2f(a2, a3);
                *(uint2*)&aT[row * 136 + lh * 4] = o;
            }
        }
    }
    __syncthreads();

    // ---- phase 2: GEMM chain (M=32, N-split waves) ----
    bf16x8 bfr[4][2];
    #pragma unroll
    for (int kc = 0; kc < 4; ++kc)
        #pragma unroll
        for (int ntl = 0; ntl < 2; ++ntl)
            bfr[kc][ntl] = *(const bf16x8*)(Wu1t + (size_t)(colbase + ntl * 16 + l15) * 128 + kc * 32 + q * 8);
    float rpre[2][2][4];
    #pragma unroll
    for (int ntl = 0; ntl < 2; ++ntl) {
        int col = colbase + ntl * 16 + l15;
        #pragma unroll
        for (int m = 0; m < 2; ++m)
            #pragma unroll
            for (int reg = 0; reg < 4; ++reg)
                rpre[ntl][m][reg] = r[(n0 + m * 16 + q * 4 + reg) * N_FEAT + col];
    }

    f32x4 acc[2][2];

    // GEMM1: h = ssp(agg @ Wu1 + bu1)
    #pragma unroll
    for (int m = 0; m < 2; ++m)
        #pragma unroll
        for (int ntl = 0; ntl < 2; ++ntl) acc[m][ntl] = (f32x4){0.f, 0.f, 0.f, 0.f};
    #pragma unroll
    for (int kc = 0; kc < 4; ++kc)
        #pragma unroll
        for (int m = 0; m < 2; ++m) {
            bf16x8 a = *(const bf16x8*)(aT + (m * 16 + l15) * 136 + kc * 32 + q * 8);
            acc[m][0] = __builtin_amdgcn_mfma_f32_16x16x32_bf16(a, bfr[kc][0], acc[m][0], 0, 0, 0);
            acc[m][1] = __builtin_amdgcn_mfma_f32_16x16x32_bf16(a, bfr[kc][1], acc[m][1], 0, 0, 0);
        }
    #pragma unroll
    for (int ntl = 0; ntl < 2; ++ntl) {
        int col = colbase + ntl * 16 + l15;
        float bv = bu1[col];
        #pragma unroll
        for (int m = 0; m < 2; ++m)
            #pragma unroll
            for (int reg = 0; reg < 4; ++reg)
                hT[(m * 16 + q * 4 + reg) * 136 + col] = (u16)f2bf_u(ssp_f(acc[m][ntl][reg] + bv));
    }
    __syncthreads();

    // GEMM2: v = h @ Wu2 + bu2 + r_old
    #pragma unroll
    for (int kc = 0; kc < 4; ++kc)
        #pragma unroll
        for (int ntl = 0; ntl < 2; ++ntl)
            bfr[kc][ntl] = *(const bf16x8*)(Wu2t + (size_t)(colbase + ntl * 16 + l15) * 128 + kc * 32 + q * 8);
    #pragma unroll
    for (int m = 0; m < 2; ++m)
        #pragma unroll
        for (int ntl = 0; ntl < 2; ++ntl) acc[m][ntl] = (f32x4){0.f, 0.f, 0.f, 0.f};
    #pragma unroll
    for (int kc = 0; kc < 4; ++kc)
        #pragma unroll
        for (int m = 0; m < 2; ++m) {
            bf16x8 a = *(const bf16x8*)(hT + (m * 16 + l15) * 136 + kc * 32 + q * 8);
            acc[m][0] = __builtin_amdgcn_mfma_f32_16x16x32_bf16(a, bfr[kc][0], acc[m][0], 0, 0, 0);
            acc[m][1] = __builtin_amdgcn_mfma_f32_16x16x32_bf16(a, bfr[kc][1], acc[m][1], 0, 0, 0);
        }
    __syncthreads();
    #pragma unroll
    for (int ntl = 0; ntl < 2; ++ntl) {
        int col = colbase + ntl * 16 + l15;
        float bv = bu2[col];
        #pragma unroll
        for (int m = 0; m < 2; ++m)
            #pragma unroll
            for (int reg = 0; reg < 4; ++reg) {
                int row = m * 16 + q * 4 + reg;
                float v = acc[m][ntl][reg] + bv + rpre[ntl][m][reg];
                if (!RO) r[(n0 + row) * N_FEAT + col] = v;
                aT[row * 136 + col] = (u16)f2bf_u(v);
            }
    }
    __syncthreads();

    // GEMM3
    #pragma unroll
    for (int kc = 0; kc < 4; ++kc)
        #pragma unroll
        for (int ntl = 0; ntl < 2; ++ntl)
            bfr[kc][ntl] = *(const bf16x8*)(W3t + (size_t)(colbase + ntl * 16 + l15) * 128 + kc * 32 + q * 8);
    #pragma unroll
    for (int m = 0; m < 2; ++m)
        #pragma unroll
        for (int ntl = 0; ntl < 2; ++ntl) acc[m][ntl] = (f32x4){0.f, 0.f, 0.f, 0.f};
    #pragma unroll
    for (int kc = 0; kc < 4; ++kc)
        #pragma unroll
        for (int m = 0; m < 2; ++m) {
            bf16x8 a = *(const bf16x8*)(aT + (m * 16 + l15) * 136 + kc * 32 + q * 8);
            acc[m][0] = __builtin_amdgcn_mfma_f32_16x16x32_bf16(a, bfr[kc][0], acc[m][0], 0, 0, 0);
            acc[m][1] = __builtin_amdgcn_mfma_f32_16x16x32_bf16(a, bfr[kc][1], acc[m][1], 0, 0, 0);
        }

    if (!RO) {
        #pragma unroll
        for (int ntl = 0; ntl < 2; ++ntl) {
            int col = colbase + ntl * 16 + l15;
            float bv = b3[col];
            #pragma unroll
            for (int m = 0; m < 2; ++m)
                #pragma unroll
                for (int reg = 0; reg < 4; ++reg) {
                    int row = m * 16 + q * 4 + reg;
                    rf_out[(n0 + row) * N_FEAT + col] = (u16)f2bf_u(acc[m][ntl][reg] + bv);
                }
        }
    } else {
        float (*red)[4][17] = (float(*)[4][17])aT;   // 32*4*17*4 = 8704 B
        __syncthreads();
        float b1v[2], w2v[2];
        #pragma unroll
        for (int ntl = 0; ntl < 2; ++ntl) {
            int col = colbase + ntl * 16 + l15;
            b1v[ntl] = b3[col];
            w2v[ntl] = Wr2[col];
        }
        #pragma unroll
        for (int m = 0; m < 2; ++m)
            #pragma unroll
            for (int reg = 0; reg < 4; ++reg) {
                float pk = ssp_f(acc[m][0][reg] + b1v[0]) * w2v[0]
                         + ssp_f(acc[m][1][reg] + b1v[1]) * w2v[1];
                red[m * 16 + q * 4 + reg][w][l15] = pk;
            }
        __syncthreads();
        if (tid < 64) {
            int row = tid & 31, key = tid >> 5;
            int atom = (int)n0 + row;
            if (atom < N_ATOMS) {
                float s = br2[key];
                #pragma unroll
                for (int j = 0; j < 16; ++j)
                    s += red[row][2 * key][j] + red[row][2 * key + 1][j];
                atomicAdd(&out[mol[atom] * 2 + key], s);
            }
        }
    }
}

// ================= host launcher =================
extern "C" void kernel_launch(void* const* d_in, const int* in_sizes, int n_in,
                              void* d_out, int out_size, void* d_ws, size_t ws_size,
                              hipStream_t stream) {
    const int*   z     = (const int*)d_in[0];
    const float* xyz   = (const float*)d_in[1];
    const int*   nbr   = (const int*)d_in[2];
    const int*   mol   = (const int*)d_in[3];
    const float* embed = (const float*)d_in[4];
    const float* We1   = (const float*)d_in[5];
    const float* be1   = (const float*)d_in[6];
    const float* We2   = (const float*)d_in[7];
    const float* be2   = (const float*)d_in[8];
    const float* Wn    = (const float*)d_in[9];
    const float* bn    = (const float*)d_in[10];
    const float* Wu1   = (const float*)d_in[11];
    const float* bu1   = (const float*)d_in[12];
    const float* Wu2   = (const float*)d_in[13];
    const float* bu2   = (const float*)d_in[14];
    const float* Wr1   = (const float*)d_in[15];
    const float* br1   = (const float*)d_in[16];
    const float* Wr2   = (const float*)d_in[17];
    const float* br2   = (const float*)d_in[18];
    float* out = (float*)d_out;

    float* ws = (float*)d_ws;
    const size_t NRP = (size_t)N_PAD * N_FEAT;
    const size_t NHP = (size_t)N_PAD * 64;
    float*  r_buf  = ws;                                     // NRP floats
    uint32* rfA    = (uint32*)(ws + NRP);                    // NHP uints
    uint32* rfB    = rfA + NHP;                              // NHP uints
    int*    cnt    = (int*)(rfB + NHP);                      // 50000 (+pad 48)
    uint32* inc32  = (uint32*)(cnt + 50048);                 // 50000*64 uints (12.8 MB)
    uint32* tblI   = inc32 + (size_t)N_ATOMS * CAP;          // 3*TBL_N*128 uints
    u16*    Wt     = (u16*)(tblI + (size_t)3 * TBL_N * 128); // 10*16384 u16
    float*  Gp     = (float*)(Wt + 10 * 16384);              // 100*128 floats

    hipMemsetAsync(d_out, 0, (size_t)out_size * sizeof(float), stream);
    hipMemsetAsync(cnt, 0, 50000 * sizeof(int), stream);

    k_uberA<<<FILL_START + NB_EDGE, 256, 0, stream>>>(
        nbr, xyz, cnt, inc32, We1, be1, We2, be2, tblI,
        Wn, bn, Wu1, Wu2, Wr1, Wt, embed, Gp);

    k_gather<<<(N_PAD * 32) / 256, 256, 0, stream>>>(z, embed, Gp, r_buf, rfA);

    const int GL = N_PAD / 32;   // 1564
    uint32* rin = rfA;
    uint32* rout = rfB;
    for (int l = 0; l < N_CONV; ++l) {
        const u16* Wu1t = Wt + (size_t)(3 + l) * 16384;
        const u16* Wu2t = Wt + (size_t)(6 + l) * 16384;
        if (l < N_CONV - 1) {
            k_layer<false><<<GL, 256, 0, stream>>>(cnt, inc32,
                                                   tblI + (size_t)l * TBL_N * 128, rin,
                                                   bu1 + l * 128, bu2 + l * 128, Wu1t, Wu2t,
                                                   Wt + (size_t)(l + 1) * 16384,
                                                   bn + (l + 1) * 128,
                                                   r_buf, (u16*)rout, Wr2, br2, mol, out);
        } else {
            k_layer<true><<<GL, 256, 0, stream>>>(cnt, inc32,
                                                  tblI + (size_t)l * TBL_N * 128, rin,
                                                  bu1 + l * 128, bu2 + l * 128, Wu1t, Wu2t,
                                                  Wt + (size_t)9 * 16384, br1,
                                                  r_buf, (u16*)rout, Wr2, br2, mol, out);
        }
        uint32* tmp = rin; rin = rout; rout = tmp;
    }
}

// Round 14
// 429.537 us; speedup vs baseline: 1.1725x; 1.1725x over previous
//
#include <hip/hip_runtime.h>
#include <math.h>

#define N_ATOMS   50000
#define N_PAD     50048
#define N_EDGES   600000
#define N_FEAT    128
#define N_GAUSS   32
#define N_CONV    3
#define N_MOLS    1000
#define HIDDEN_RO 64
#define CAP       64

#define TBL_N     7681
#define TBL_BPL   121
#define TBL_SCALE 1024.0f
#define TBL_TMAX  7679.0f
#define NB_EDGE   2344           // 293 chunks x 8 classes
#define NB_BUILD  (N_CONV * TBL_BPL)   // 363
#define NB_EMBG   7
#define NB_WPREP  40

typedef unsigned int   uint32;
typedef unsigned short u16;
typedef __attribute__((ext_vector_type(8))) short bf16x8;
typedef __attribute__((ext_vector_type(4))) float f32x4;

__device__ __forceinline__ float ssp_f(float x) {
    float e = __expf(-fabsf(x));
    return fmaxf(x, 0.0f) + __logf(1.0f + e) - 0.6931471805599453f;
}
__device__ __forceinline__ uint32 f2bf_u(float x) {
    uint32 u = __float_as_uint(x);
    return (u + 0x7fffu + ((u >> 16) & 1u)) >> 16;
}
__device__ __forceinline__ uint32 pack2f(float a, float b) {
    return f2bf_u(a) | (f2bf_u(b) << 16);
}
__device__ __forceinline__ float bf_lo(uint32 u) { return __uint_as_float(u << 16); }
__device__ __forceinline__ float bf_hi(uint32 u) { return __uint_as_float(u & 0xffff0000u); }

// Wt layout (per matrix, 16384 u16): [kc(4)][colgrp(8)][lane(64)][j(8)]
//   lane = q*16 + l15 ; element = W[k = kc*32 + q*8 + j][col = colgrp*16 + l15]
// -> a wave's (kc, colgrp) B-fragment block is 1024 u16 contiguous: 16B/lane coalesced.

// ================= uber-A: build | embG | wprep | XCD-classed dist+fill =================
#define FILL_START (NB_BUILD + NB_EMBG + NB_WPREP)   // 410
__global__ __launch_bounds__(256)
void k_uberA(const int* __restrict__ nbr, const float* __restrict__ xyz,
             int* __restrict__ cnt, uint32* __restrict__ inc32,
             const float* __restrict__ We1_all, const float* __restrict__ be1_all,
             const float* __restrict__ We2_all, const float* __restrict__ be2_all,
             uint32* __restrict__ tblI,
             const float* __restrict__ Wn, const float* __restrict__ bn,
             const float* __restrict__ Wu1,
             const float* __restrict__ Wu2, const float* __restrict__ Wr1,
             u16* __restrict__ Wt, const float* __restrict__ embed,
             float* __restrict__ Gp) {
    __shared__ float smemA[26112 / 4];
    int b = blockIdx.x;
    int t = threadIdx.x;

    if (b < NB_BUILD) {
        int l    = b / TBL_BPL;
        int row0 = (b % TBL_BPL) * 64;
        const float* We1 = We1_all + (size_t)l * N_GAUSS * N_FEAT;
        const float* be1 = be1_all + (size_t)l * N_FEAT;
        const float* We2 = We2_all + (size_t)l * N_FEAT * N_FEAT;
        const float* be2 = be2_all + (size_t)l * N_FEAT;
        uint32* tl = tblI + (size_t)l * TBL_N * 128;
        float (*gT)[68] = (float(*)[68])smemA;
        u16* h1T = (u16*)(smemA + 32 * 68);

        const float width = 5.0f / 31.0f;
        const float coef = -0.5f / (width * width);
        #pragma unroll
        for (int i = 0; i < 8; ++i) {
            int idx = t + 256 * i;
            int g = idx >> 6, e = idx & 63;
            float d = (float)(row0 + e) * (1.0f / TBL_SCALE);
            float diff = d - (float)g * width;
            gT[g][e] = __expf(coef * diff * diff);
        }
        __syncthreads();

        int tf = t & 15, te = t >> 4;
        int f0 = tf * 8, eb = te * 4;
        float acc[4][8];
        #pragma unroll
        for (int i = 0; i < 4; ++i)
            #pragma unroll
            for (int j = 0; j < 8; ++j) acc[i][j] = 0.0f;

        #pragma unroll 4
        for (int g = 0; g < N_GAUSS; ++g) {
            float4 a  = *(const float4*)&gT[g][eb];
            float4 w0 = *(const float4*)(We1 + g * N_FEAT + f0);
            float4 w1 = *(const float4*)(We1 + g * N_FEAT + f0 + 4);
            float av[4] = {a.x, a.y, a.z, a.w};
            float wv[8] = {w0.x, w0.y, w0.z, w0.w, w1.x, w1.y, w1.z, w1.w};
            #pragma unroll
            for (int i = 0; i < 4; ++i)
                #pragma unroll
                for (int j = 0; j < 8; ++j) acc[i][j] += av[i] * wv[j];
        }
        #pragma unroll
        for (int j = 0; j < 8; ++j) {
            float bb2 = be1[f0 + j];
            uint2 hv;
            hv.x = pack2f(ssp_f(acc[0][j] + bb2), ssp_f(acc[1][j] + bb2));
            hv.y = pack2f(ssp_f(acc[2][j] + bb2), ssp_f(acc[3][j] + bb2));
            *(uint2*)&h1T[(f0 + j) * 68 + eb] = hv;
        }
        __syncthreads();

        #pragma unroll
        for (int i = 0; i < 4; ++i)
            #pragma unroll
            for (int j = 0; j < 8; ++j) acc[i][j] = 0.0f;
        #pragma unroll 2
        for (int c = 0; c < N_FEAT; ++c) {
            uint2 hv = *(const uint2*)&h1T[c * 68 + eb];
            float av[4] = {bf_lo(hv.x), bf_hi(hv.x), bf_lo(hv.y), bf_hi(hv.y)};
            float4 w0 = *(const float4*)(We2 + c * N_FEAT + f0);
            float4 w1 = *(const float4*)(We2 + c * N_FEAT + f0 + 4);
            float wv[8] = {w0.x, w0.y, w0.z, w0.w, w1.x, w1.y, w1.z, w1.w};
            #pragma unroll
            for (int i = 0; i < 4; ++i)
                #pragma unroll
                for (int j = 0; j < 8; ++j) acc[i][j] += av[i] * wv[j];
        }
        __syncthreads();

        uint32* pvS = (uint32*)smemA;   // [64][65]
        #pragma unroll
        for (int i = 0; i < 4; ++i)
            #pragma unroll
            for (int p = 0; p < 4; ++p)
                pvS[(eb + i) * 65 + tf * 4 + p] =
                    pack2f(acc[i][2 * p]     + be2[f0 + 2 * p],
                           acc[i][2 * p + 1] + be2[f0 + 2 * p + 1]);
        __syncthreads();

        #pragma unroll
        for (int i = 0; i < 16; ++i) {
            int idx = t + 256 * i;
            int e = idx >> 6, fp = idx & 63;
            int ent = row0 + e;
            if (ent < TBL_N - 1) {
                if (e < 63) {
                    uint2 v2;
                    v2.x = pvS[e * 65 + fp];
                    v2.y = pvS[(e + 1) * 65 + fp];
                    *(uint2*)(tl + ((size_t)ent * 64 + fp) * 2) = v2;
                } else {
                    tl[((size_t)ent * 64 + fp) * 2] = pvS[63 * 65 + fp];
                }
            }
        }
        if (row0 > 0 && t < 64)
            tl[((size_t)(row0 - 1) * 64 + t) * 2 + 1] = pvS[t];
        return;
    }
    if (b < NB_BUILD + NB_EMBG) {
        int bb = b - NB_BUILD;
        int row = bb * 16 + (t >> 4);
        int tf = t & 15;
        if (row < 100) {
            float acc[8];
            #pragma unroll
            for (int j = 0; j < 8; ++j) acc[j] = 0.0f;
            for (int k = 0; k < N_FEAT; ++k) {
                float a = embed[row * N_FEAT + k];
                float4 w0 = *(const float4*)(Wn + k * N_FEAT + tf * 8);
                float4 w1 = *(const float4*)(Wn + k * N_FEAT + tf * 8 + 4);
                acc[0] += a * w0.x; acc[1] += a * w0.y;
                acc[2] += a * w0.z; acc[3] += a * w0.w;
                acc[4] += a * w1.x; acc[5] += a * w1.y;
                acc[6] += a * w1.z; acc[7] += a * w1.w;
            }
            #pragma unroll
            for (int j = 0; j < 8; ++j)
                Gp[row * N_FEAT + tf * 8 + j] = acc[j] + bn[tf * 8 + j];
        }
        return;
    }
    if (b < FILL_START) {
        // weight prep -> fragment-coalesced layout
        int wb = b - NB_BUILD - NB_EMBG;
        int gid = wb * 256 + t;
        #pragma unroll
        for (int i = 0; i < 16; ++i) {
            int idx = gid + i * (NB_WPREP * 256);
            int j    = idx & 7;
            int lane = (idx >> 3) & 63;
            int cg   = (idx >> 9) & 7;
            int kc   = (idx >> 12) & 3;
            int mat  = idx >> 14;
            int col  = cg * 16 + (lane & 15);
            int k    = kc * 32 + (lane >> 4) * 8 + j;
            float v;
            if (mat < 3)      v = Wn [(size_t)mat * 16384 + k * 128 + col];
            else if (mat < 6) v = Wu1[(size_t)(mat - 3) * 16384 + k * 128 + col];
            else if (mat < 9) v = Wu2[(size_t)(mat - 6) * 16384 + k * 128 + col];
            else { int key = col >> 6, h = col & 63; v = Wr1[(size_t)key * 128 * 64 + k * 64 + h]; }
            Wt[(size_t)idx] = (u16)f2bf_u(v);
        }
        return;
    }
    // ---- dist + fill, XCD-class partitioned ----
    {
        int cls = b & 7;
        int base = ((b - FILL_START) >> 3) * 2048;
        #pragma unroll
        for (int i = 0; i < 8; ++i) {
            int e = base + t + 256 * i;
            if (e < N_EDGES) {
                int a0 = nbr[2 * e], a1 = nbr[2 * e + 1];
                bool m0 = (a0 & 7) == cls, m1 = (a1 & 7) == cls;
                if (m0 | m1) {
                    float dx = xyz[3 * a0]     - xyz[3 * a1];
                    float dy = xyz[3 * a0 + 1] - xyz[3 * a1 + 1];
                    float dz = xyz[3 * a0 + 2] - xyz[3 * a1 + 2];
                    float d = sqrtf(dx * dx + dy * dy + dz * dz);
                    float tv = fminf(d * TBL_SCALE, TBL_TMAX);
                    uint32 tq = (uint32)(tv * 8.0f + 0.5f);
                    if (m1) {
                        int p1 = atomicAdd(&cnt[a1], 1);
                        if (p1 < CAP) inc32[((size_t)a1 << 6) | p1] = ((uint32)a0 << 16) | tq;
                    }
                    if (m0) {
                        int p0 = atomicAdd(&cnt[a0], 1);
                        if (p0 < CAP) inc32[((size_t)a0 << 6) | p0] = ((uint32)a1 << 16) | tq;
                    }
                }
            }
        }
    }
}

// ================= gather: r = embed[z], rf16 = bf16(G'[z]) =================
__global__ __launch_bounds__(256)
void k_gather(const int* __restrict__ z, const float* __restrict__ embed,
              const float* __restrict__ Gp, float* __restrict__ r,
              uint32* __restrict__ rf16) {
    int idx = blockIdx.x * 256 + threadIdx.x;
    if (idx >= N_PAD * 32) return;
    int n = idx >> 5, c4 = idx & 31;
    int zz = z[n < N_ATOMS ? n : 0];
    float4 v = *(const float4*)(embed + (size_t)zz * N_FEAT + c4 * 4);
    *(float4*)(r + (size_t)n * N_FEAT + c4 * 4) = v;
    float4 g = *(const float4*)(Gp + (size_t)zz * N_FEAT + c4 * 4);
    uint2 o;
    o.x = pack2f(g.x, g.y);
    o.y = pack2f(g.z, g.w);
    *(uint2*)(rf16 + (size_t)n * 64 + c4 * 2) = o;
}

// ================= gather aggregation (bucketed inc32) =================
__global__ __launch_bounds__(256)
void k_agg(const int* __restrict__ cnt, const uint32* __restrict__ inc32,
           const uint32* __restrict__ tblI, const uint32* __restrict__ rf,
           uint32* __restrict__ agg16) {
    int wv = threadIdx.x >> 6, lane = threadIdx.x & 63;
    int h = lane >> 5, lh = lane & 31;
    int n = blockIdx.x * 4 + wv;
    if (n >= N_ATOMS) return;
    int s = n << 6;
    int e = s + min(cnt[n], CAP);
    float a0 = 0.f, a1 = 0.f, a2 = 0.f, a3 = 0.f;
    int i = s;
    for (; i + 8 <= e; i += 8) {
        uint32 v[4];
        #pragma unroll
        for (int u = 0; u < 4; ++u) v[u] = inc32[i + 2 * u + h];
        int i0[4], oa[4];
        float fr[4];
        #pragma unroll
        for (int u = 0; u < 4; ++u) {
            oa[u] = v[u] >> 16;
            uint32 tq = v[u] & 0xffffu;
            i0[u] = tq >> 3;
            fr[u] = (float)(tq & 7u) * 0.125f;
        }
        uint4 T[4];
        #pragma unroll
        for (int u = 0; u < 4; ++u) T[u] = *(const uint4*)(tblI + ((size_t)i0[u] * 64 + lh * 2) * 2);
        uint2 R[4];
        #pragma unroll
        for (int u = 0; u < 4; ++u) R[u] = *(const uint2*)(rf + (size_t)oa[u] * 64 + lh * 2);
        #pragma unroll
        for (int u = 0; u < 4; ++u) {
            float e0 = fmaf(fr[u], bf_lo(T[u].y) - bf_lo(T[u].x), bf_lo(T[u].x));
            float e1 = fmaf(fr[u], bf_hi(T[u].y) - bf_hi(T[u].x), bf_hi(T[u].x));
            float e2 = fmaf(fr[u], bf_lo(T[u].w) - bf_lo(T[u].z), bf_lo(T[u].z));
            float e3 = fmaf(fr[u], bf_hi(T[u].w) - bf_hi(T[u].z), bf_hi(T[u].z));
            a0 = fmaf(e0, bf_lo(R[u].x), a0);
            a1 = fmaf(e1, bf_hi(R[u].x), a1);
            a2 = fmaf(e2, bf_lo(R[u].y), a2);
            a3 = fmaf(e3, bf_hi(R[u].y), a3);
        }
    }
    for (; i < e; i += 2) {
        int idx = i + h;
        bool ok = idx < e;
        uint32 v = inc32[ok ? idx : s];
        int oa = v >> 16;
        uint32 tq = v & 0xffffu;
        int i0 = tq >> 3;
        float fr = (float)(tq & 7u) * 0.125f;
        uint4 T = *(const uint4*)(tblI + ((size_t)i0 * 64 + lh * 2) * 2);
        uint2 R = *(const uint2*)(rf + (size_t)oa * 64 + lh * 2);
        float m = ok ? 1.0f : 0.0f;
        float e0 = fmaf(fr, bf_lo(T.y) - bf_lo(T.x), bf_lo(T.x));
        float e1 = fmaf(fr, bf_hi(T.y) - bf_hi(T.x), bf_hi(T.x));
        float e2 = fmaf(fr, bf_lo(T.w) - bf_lo(T.z), bf_lo(T.z));
        float e3 = fmaf(fr, bf_hi(T.w) - bf_hi(T.z), bf_hi(T.z));
        a0 = fmaf(e0, m * bf_lo(R.x), a0);
        a1 = fmaf(e1, m * bf_hi(R.x), a1);
        a2 = fmaf(e2, m * bf_lo(R.y), a2);
        a3 = fmaf(e3, m * bf_hi(R.y), a3);
    }
    a0 += __shfl_xor(a0, 32);
    a1 += __shfl_xor(a1, 32);
    a2 += __shfl_xor(a2, 32);
    a3 += __shfl_xor(a3, 32);
    if (h == 0) {
        uint2 o;
        o.x = pack2f(a0, a1);
        o.y = pack2f(a2, a3);
        *(uint2*)(agg16 + (size_t)n * 64 + lh * 2) = o;
    }
}

// ================= fused update (M=32, coalesced B-frag loads) =================
// B-frag for (kc, ntl): Wmat + kc*4096 + (w*2+ntl)*512 + lane*8   (u16 units)
template <bool RO>
__global__ __launch_bounds__(256)
void k_update(const u16* __restrict__ agg16u,
              const float* __restrict__ bu1, const float* __restrict__ bu2,
              const u16* __restrict__ Wu1t, const u16* __restrict__ Wu2t,
              const u16* __restrict__ W3t, const float* __restrict__ b3,
              float* __restrict__ r, u16* __restrict__ rf16,
              const float* __restrict__ Wr2, const float* __restrict__ br2,
              const int* __restrict__ mol, float* __restrict__ out) {
    __shared__ u16 aT[32 * 136];   // 8704 B; re-used as red[32][4][17] in RO epilogue
    __shared__ u16 hT[32 * 136];

    int tid = threadIdx.x;
    int w = tid >> 6, lane = tid & 63;
    int l15 = lane & 15, q = lane >> 4;
    int colbase = w * 32;
    size_t n0 = (size_t)blockIdx.x * 32;
    size_t fragoff = (size_t)(w * 2) * 512 + (size_t)lane * 8;   // + ntl*512 + kc*4096

    // ---- prefetch: GEMM1 B-frags (coalesced) + GEMM2 residual r-tile ----
    bf16x8 bfr[4][2];
    #pragma unroll
    for (int kc = 0; kc < 4; ++kc)
        #pragma unroll
        for (int ntl = 0; ntl < 2; ++ntl)
            bfr[kc][ntl] = *(const bf16x8*)(Wu1t + kc * 4096 + ntl * 512 + fragoff);
    float rpre[2][2][4];
    #pragma unroll
    for (int ntl = 0; ntl < 2; ++ntl) {
        int col = colbase + ntl * 16 + l15;
        #pragma unroll
        for (int m = 0; m < 2; ++m)
            #pragma unroll
            for (int reg = 0; reg < 4; ++reg)
                rpre[ntl][m][reg] = r[(n0 + m * 16 + q * 4 + reg) * N_FEAT + col];
    }

    // stage agg -> aT
    #pragma unroll
    for (int i = 0; i < 2; ++i) {
        int idx = tid + 256 * i;
        int row = idx >> 4, c = idx & 15;
        uint4 v = *(const uint4*)(agg16u + (n0 + row) * 128 + c * 8);
        *(uint4*)&aT[row * 136 + c * 8] = v;
    }
    __syncthreads();

    f32x4 acc[2][2];

    // ---- GEMM1: h = ssp(agg @ Wu1 + bu1) ----
    #pragma unroll
    for (int m = 0; m < 2; ++m)
        #pragma unroll
        for (int ntl = 0; ntl < 2; ++ntl) acc[m][ntl] = (f32x4){0.f, 0.f, 0.f, 0.f};
    #pragma unroll
    for (int kc = 0; kc < 4; ++kc)
        #pragma unroll
        for (int m = 0; m < 2; ++m) {
            bf16x8 a = *(const bf16x8*)(aT + (m * 16 + l15) * 136 + kc * 32 + q * 8);
            acc[m][0] = __builtin_amdgcn_mfma_f32_16x16x32_bf16(a, bfr[kc][0], acc[m][0], 0, 0, 0);
            acc[m][1] = __builtin_amdgcn_mfma_f32_16x16x32_bf16(a, bfr[kc][1], acc[m][1], 0, 0, 0);
        }
    #pragma unroll
    for (int ntl = 0; ntl < 2; ++ntl) {
        int col = colbase + ntl * 16 + l15;
        float bv = bu1[col];
        #pragma unroll
        for (int m = 0; m < 2; ++m)
            #pragma unroll
            for (int reg = 0; reg < 4; ++reg)
                hT[(m * 16 + q * 4 + reg) * 136 + col] = (u16)f2bf_u(ssp_f(acc[m][ntl][reg] + bv));
    }
    __syncthreads();

    // ---- GEMM2: v = h @ Wu2 + bu2 + r_old ----
    #pragma unroll
    for (int kc = 0; kc < 4; ++kc)
        #pragma unroll
        for (int ntl = 0; ntl < 2; ++ntl)
            bfr[kc][ntl] = *(const bf16x8*)(Wu2t + kc * 4096 + ntl * 512 + fragoff);
    #pragma unroll
    for (int m = 0; m < 2; ++m)
        #pragma unroll
        for (int ntl = 0; ntl < 2; ++ntl) acc[m][ntl] = (f32x4){0.f, 0.f, 0.f, 0.f};
    #pragma unroll
    for (int kc = 0; kc < 4; ++kc)
        #pragma unroll
        for (int m = 0; m < 2; ++m) {
            bf16x8 a = *(const bf16x8*)(hT + (m * 16 + l15) * 136 + kc * 32 + q * 8);
            acc[m][0] = __builtin_amdgcn_mfma_f32_16x16x32_bf16(a, bfr[kc][0], acc[m][0], 0, 0, 0);
            acc[m][1] = __builtin_amdgcn_mfma_f32_16x16x32_bf16(a, bfr[kc][1], acc[m][1], 0, 0, 0);
        }
    __syncthreads();
    #pragma unroll
    for (int ntl = 0; ntl < 2; ++ntl) {
        int col = colbase + ntl * 16 + l15;
        float bv = bu2[col];
        #pragma unroll
        for (int m = 0; m < 2; ++m)
            #pragma unroll
            for (int reg = 0; reg < 4; ++reg) {
                int row = m * 16 + q * 4 + reg;
                float v = acc[m][ntl][reg] + bv + rpre[ntl][m][reg];
                if (!RO) r[(n0 + row) * N_FEAT + col] = v;
                aT[row * 136 + col] = (u16)f2bf_u(v);
            }
    }
    __syncthreads();

    // ---- GEMM3 ----
    #pragma unroll
    for (int kc = 0; kc < 4; ++kc)
        #pragma unroll
        for (int ntl = 0; ntl < 2; ++ntl)
            bfr[kc][ntl] = *(const bf16x8*)(W3t + kc * 4096 + ntl * 512 + fragoff);
    #pragma unroll
    for (int m = 0; m < 2; ++m)
        #pragma unroll
        for (int ntl = 0; ntl < 2; ++ntl) acc[m][ntl] = (f32x4){0.f, 0.f, 0.f, 0.f};
    #pragma unroll
    for (int kc = 0; kc < 4; ++kc)
        #pragma unroll
        for (int m = 0; m < 2; ++m) {
            bf16x8 a = *(const bf16x8*)(aT + (m * 16 + l15) * 136 + kc * 32 + q * 8);
            acc[m][0] = __builtin_amdgcn_mfma_f32_16x16x32_bf16(a, bfr[kc][0], acc[m][0], 0, 0, 0);
            acc[m][1] = __builtin_amdgcn_mfma_f32_16x16x32_bf16(a, bfr[kc][1], acc[m][1], 0, 0, 0);
        }

    if (!RO) {
        #pragma unroll
        for (int ntl = 0; ntl < 2; ++ntl) {
            int col = colbase + ntl * 16 + l15;
            float bv = b3[col];
            #pragma unroll
            for (int m = 0; m < 2; ++m)
                #pragma unroll
                for (int reg = 0; reg < 4; ++reg) {
                    int row = m * 16 + q * 4 + reg;
                    rf16[(n0 + row) * N_FEAT + col] = (u16)f2bf_u(acc[m][ntl][reg] + bv);
                }
        }
    } else {
        float (*red)[4][17] = (float(*)[4][17])aT;   // 8704 B
        __syncthreads();
        float b1v[2], w2v[2];
        #pragma unroll
        for (int ntl = 0; ntl < 2; ++ntl) {
            int col = colbase + ntl * 16 + l15;
            b1v[ntl] = b3[col];
            w2v[ntl] = Wr2[col];
        }
        #pragma unroll
        for (int m = 0; m < 2; ++m)
            #pragma unroll
            for (int reg = 0; reg < 4; ++reg) {
                float pk = ssp_f(acc[m][0][reg] + b1v[0]) * w2v[0]
                         + ssp_f(acc[m][1][reg] + b1v[1]) * w2v[1];
                red[m * 16 + q * 4 + reg][w][l15] = pk;
            }
        __syncthreads();
        if (tid < 64) {
            int row = tid & 31, key = tid >> 5;
            int atom = (int)n0 + row;
            if (atom < N_ATOMS) {
                float s = br2[key];
                #pragma unroll
                for (int j = 0; j < 16; ++j)
                    s += red[row][2 * key][j] + red[row][2 * key + 1][j];
                atomicAdd(&out[mol[atom] * 2 + key], s);
            }
        }
    }
}

// ================= host launcher =================
extern "C" void kernel_launch(void* const* d_in, const int* in_sizes, int n_in,
                              void* d_out, int out_size, void* d_ws, size_t ws_size,
                              hipStream_t stream) {
    const int*   z     = (const int*)d_in[0];
    const float* xyz   = (const float*)d_in[1];
    const int*   nbr   = (const int*)d_in[2];
    const int*   mol   = (const int*)d_in[3];
    const float* embed = (const float*)d_in[4];
    const float* We1   = (const float*)d_in[5];
    const float* be1   = (const float*)d_in[6];
    const float* We2   = (const float*)d_in[7];
    const float* be2   = (const float*)d_in[8];
    const float* Wn    = (const float*)d_in[9];
    const float* bn    = (const float*)d_in[10];
    const float* Wu1   = (const float*)d_in[11];
    const float* bu1   = (const float*)d_in[12];
    const float* Wu2   = (const float*)d_in[13];
    const float* bu2   = (const float*)d_in[14];
    const float* Wr1   = (const float*)d_in[15];
    const float* br1   = (const float*)d_in[16];
    const float* Wr2   = (const float*)d_in[17];
    const float* br2   = (const float*)d_in[18];
    float* out = (float*)d_out;

    float* ws = (float*)d_ws;
    const size_t NRP = (size_t)N_PAD * N_FEAT;
    const size_t NHP = (size_t)N_PAD * 64;
    float*  r_buf  = ws;
    uint32* agg16  = (uint32*)(ws + NRP);
    uint32* rf16   = agg16 + NHP;
    int*    cnt    = (int*)(rf16 + NHP);
    uint32* inc32  = (uint32*)(cnt + 50048);
    uint32* tblI   = inc32 + (size_t)N_ATOMS * CAP;
    u16*    Wt     = (u16*)(tblI + (size_t)3 * TBL_N * 128);
    float*  Gp     = (float*)(Wt + 10 * 16384);

    hipMemsetAsync(d_out, 0, (size_t)out_size * sizeof(float), stream);
    hipMemsetAsync(cnt, 0, 50000 * sizeof(int), stream);

    k_uberA<<<FILL_START + NB_EDGE, 256, 0, stream>>>(
        nbr, xyz, cnt, inc32, We1, be1, We2, be2, tblI,
        Wn, bn, Wu1, Wu2, Wr1, Wt, embed, Gp);

    k_gather<<<(N_PAD * 32) / 256, 256, 0, stream>>>(z, embed, Gp, r_buf, rf16);

    const int GA2 = N_PAD / 32;   // 1564
    for (int l = 0; l < N_CONV; ++l) {
        k_agg<<<(N_ATOMS + 3) / 4, 256, 0, stream>>>(cnt, inc32,
                                                     tblI + (size_t)l * TBL_N * 128,
                                                     rf16, agg16);
        const u16* Wu1t = Wt + (size_t)(3 + l) * 16384;
        const u16* Wu2t = Wt + (size_t)(6 + l) * 16384;
        if (l < N_CONV - 1) {
            k_update<false><<<GA2, 256, 0, stream>>>((const u16*)agg16, bu1 + l * 128,
                                                     bu2 + l * 128, Wu1t, Wu2t,
                                                     Wt + (size_t)(l + 1) * 16384,
                                                     bn + (l + 1) * 128,
                                                     r_buf, (u16*)rf16, Wr2, br2, mol, out);
        } else {
            k_update<true><<<GA2, 256, 0, stream>>>((const u16*)agg16, bu1 + l * 128,
                                                    bu2 + l * 128, Wu1t, Wu2t,
                                                    Wt + (size_t)9 * 16384, br1,
                                                    r_buf, (u16*)rf16, Wr2, br2, mol, out);
        }
    }
}

// Round 15
// 412.320 us; speedup vs baseline: 1.2214x; 1.0418x over previous
//
#include <hip/hip_runtime.h>
#include <math.h>

#define N_ATOMS   50000
#define N_PAD     50048
#define N_EDGES   600000
#define N_FEAT    128
#define N_GAUSS   32
#define N_CONV    3
#define N_MOLS    1000
#define HIDDEN_RO 64
#define CAP       64

#define TBL_N     1921           // rows per layer, d = i/256, covers [0, 7.5]
#define TBL_BPL   31             // 31*64 = 1984 >= 1921
#define TBL_SCALE 256.0f
#define TBL_TMAX  1919.0f        // clamp so i0+1 <= 1920
#define NB_EDGE   2344           // 293 chunks x 8 classes
#define NB_BUILD  (N_CONV * TBL_BPL)   // 93
#define NB_EMBG   7
#define NB_WPREP  40

typedef unsigned int   uint32;
typedef unsigned short u16;
typedef __attribute__((ext_vector_type(8))) short bf16x8;
typedef __attribute__((ext_vector_type(4))) float f32x4;

__device__ __forceinline__ float ssp_f(float x) {
    float e = __expf(-fabsf(x));
    return fmaxf(x, 0.0f) + __logf(1.0f + e) - 0.6931471805599453f;
}
__device__ __forceinline__ uint32 f2bf_u(float x) {
    uint32 u = __float_as_uint(x);
    return (u + 0x7fffu + ((u >> 16) & 1u)) >> 16;
}
__device__ __forceinline__ uint32 pack2f(float a, float b) {
    return f2bf_u(a) | (f2bf_u(b) << 16);
}
__device__ __forceinline__ float bf_lo(uint32 u) { return __uint_as_float(u << 16); }
__device__ __forceinline__ float bf_hi(uint32 u) { return __uint_as_float(u & 0xffff0000u); }

// Wt layout (per matrix, 16384 u16): [kc(4)][colgrp(8)][lane(64)][j(8)]
// -> wave's (kc,colgrp) B-frag block is contiguous: 16B/lane coalesced.

// ================= uber-A: build | embG | wprep | XCD-classed dist+fill =================
#define FILL_START (NB_BUILD + NB_EMBG + NB_WPREP)   // 140
__global__ __launch_bounds__(256)
void k_uberA(const int* __restrict__ nbr, const float* __restrict__ xyz,
             int* __restrict__ cnt, uint32* __restrict__ inc32,
             const float* __restrict__ We1_all, const float* __restrict__ be1_all,
             const float* __restrict__ We2_all, const float* __restrict__ be2_all,
             uint32* __restrict__ tblI,
             const float* __restrict__ Wn, const float* __restrict__ bn,
             const float* __restrict__ Wu1,
             const float* __restrict__ Wu2, const float* __restrict__ Wr1,
             u16* __restrict__ Wt, const float* __restrict__ embed,
             float* __restrict__ Gp) {
    __shared__ float smemA[17408 / 4];   // h1T bf16 [128][68]; later pvS [64][65] uint32
    int b = blockIdx.x;
    int t = threadIdx.x;

    if (b < NB_BUILD) {
        int l    = b / TBL_BPL;
        int row0 = (b % TBL_BPL) * 64;
        const float* We1 = We1_all + (size_t)l * N_GAUSS * N_FEAT;
        const float* be1 = be1_all + (size_t)l * N_FEAT;
        const float* We2 = We2_all + (size_t)l * N_FEAT * N_FEAT;
        const float* be2 = be2_all + (size_t)l * N_FEAT;
        uint32* tl = tblI + (size_t)l * TBL_N * 128;
        u16* h1T = (u16*)smemA;          // [128][68]

        const float width = 5.0f / 31.0f;
        const float coef = -0.5f / (width * width);

        int tf = t & 15, te = t >> 4;
        int f0 = tf * 8, eb = te * 4;
        float dloc[4];
        #pragma unroll
        for (int i = 0; i < 4; ++i) dloc[i] = (float)(row0 + eb + i) * (1.0f / TBL_SCALE);

        float acc[4][8];
        #pragma unroll
        for (int i = 0; i < 4; ++i)
            #pragma unroll
            for (int j = 0; j < 8; ++j) acc[i][j] = 0.0f;

        // GEMM1 with register-computed gaussians (no gT LDS)
        for (int g = 0; g < N_GAUSS; ++g) {
            float mu = (float)g * width;
            float av[4];
            #pragma unroll
            for (int i = 0; i < 4; ++i) {
                float diff = dloc[i] - mu;
                av[i] = __expf(coef * diff * diff);
            }
            float4 w0 = *(const float4*)(We1 + g * N_FEAT + f0);
            float4 w1 = *(const float4*)(We1 + g * N_FEAT + f0 + 4);
            float wv[8] = {w0.x, w0.y, w0.z, w0.w, w1.x, w1.y, w1.z, w1.w};
            #pragma unroll
            for (int i = 0; i < 4; ++i)
                #pragma unroll
                for (int j = 0; j < 8; ++j) acc[i][j] += av[i] * wv[j];
        }
        #pragma unroll
        for (int j = 0; j < 8; ++j) {
            float bb2 = be1[f0 + j];
            uint2 hv;
            hv.x = pack2f(ssp_f(acc[0][j] + bb2), ssp_f(acc[1][j] + bb2));
            hv.y = pack2f(ssp_f(acc[2][j] + bb2), ssp_f(acc[3][j] + bb2));
            *(uint2*)&h1T[(f0 + j) * 68 + eb] = hv;
        }
        __syncthreads();

        #pragma unroll
        for (int i = 0; i < 4; ++i)
            #pragma unroll
            for (int j = 0; j < 8; ++j) acc[i][j] = 0.0f;
        #pragma unroll 2
        for (int c = 0; c < N_FEAT; ++c) {
            uint2 hv = *(const uint2*)&h1T[c * 68 + eb];
            float av[4] = {bf_lo(hv.x), bf_hi(hv.x), bf_lo(hv.y), bf_hi(hv.y)};
            float4 w0 = *(const float4*)(We2 + c * N_FEAT + f0);
            float4 w1 = *(const float4*)(We2 + c * N_FEAT + f0 + 4);
            float wv[8] = {w0.x, w0.y, w0.z, w0.w, w1.x, w1.y, w1.z, w1.w};
            #pragma unroll
            for (int i = 0; i < 4; ++i)
                #pragma unroll
                for (int j = 0; j < 8; ++j) acc[i][j] += av[i] * wv[j];
        }
        __syncthreads();   // all h1T reads done -> reuse as pvS

        uint32* pvS = (uint32*)smemA;   // [64][65]
        #pragma unroll
        for (int i = 0; i < 4; ++i)
            #pragma unroll
            for (int p = 0; p < 4; ++p)
                pvS[(eb + i) * 65 + tf * 4 + p] =
                    pack2f(acc[i][2 * p]     + be2[f0 + 2 * p],
                           acc[i][2 * p + 1] + be2[f0 + 2 * p + 1]);
        __syncthreads();

        #pragma unroll
        for (int i = 0; i < 16; ++i) {
            int idx = t + 256 * i;
            int e = idx >> 6, fp = idx & 63;
            int ent = row0 + e;
            if (ent < TBL_N - 1) {
                if (e < 63) {
                    uint2 v2;
                    v2.x = pvS[e * 65 + fp];
                    v2.y = pvS[(e + 1) * 65 + fp];
                    *(uint2*)(tl + ((size_t)ent * 64 + fp) * 2) = v2;
                } else {
                    tl[((size_t)ent * 64 + fp) * 2] = pvS[63 * 65 + fp];
                }
            }
        }
        if (row0 > 0 && t < 64)
            tl[((size_t)(row0 - 1) * 64 + t) * 2 + 1] = pvS[t];
        return;
    }
    if (b < NB_BUILD + NB_EMBG) {
        int bb = b - NB_BUILD;
        int row = bb * 16 + (t >> 4);
        int tf = t & 15;
        if (row < 100) {
            float acc[8];
            #pragma unroll
            for (int j = 0; j < 8; ++j) acc[j] = 0.0f;
            for (int k = 0; k < N_FEAT; ++k) {
                float a = embed[row * N_FEAT + k];
                float4 w0 = *(const float4*)(Wn + k * N_FEAT + tf * 8);
                float4 w1 = *(const float4*)(Wn + k * N_FEAT + tf * 8 + 4);
                acc[0] += a * w0.x; acc[1] += a * w0.y;
                acc[2] += a * w0.z; acc[3] += a * w0.w;
                acc[4] += a * w1.x; acc[5] += a * w1.y;
                acc[6] += a * w1.z; acc[7] += a * w1.w;
            }
            #pragma unroll
            for (int j = 0; j < 8; ++j)
                Gp[row * N_FEAT + tf * 8 + j] = acc[j] + bn[tf * 8 + j];
        }
        return;
    }
    if (b < FILL_START) {
        // weight prep -> fragment-coalesced layout
        int wb = b - NB_BUILD - NB_EMBG;
        int gid = wb * 256 + t;
        #pragma unroll
        for (int i = 0; i < 16; ++i) {
            int idx = gid + i * (NB_WPREP * 256);
            int j    = idx & 7;
            int lane = (idx >> 3) & 63;
            int cg   = (idx >> 9) & 7;
            int kc   = (idx >> 12) & 3;
            int mat  = idx >> 14;
            int col  = cg * 16 + (lane & 15);
            int k    = kc * 32 + (lane >> 4) * 8 + j;
            float v;
            if (mat < 3)      v = Wn [(size_t)mat * 16384 + k * 128 + col];
            else if (mat < 6) v = Wu1[(size_t)(mat - 3) * 16384 + k * 128 + col];
            else if (mat < 9) v = Wu2[(size_t)(mat - 6) * 16384 + k * 128 + col];
            else { int key = col >> 6, h = col & 63; v = Wr1[(size_t)key * 128 * 64 + k * 64 + h]; }
            Wt[(size_t)idx] = (u16)f2bf_u(v);
        }
        return;
    }
    // ---- dist + fill, XCD-class partitioned ----
    {
        int cls = b & 7;
        int base = ((b - FILL_START) >> 3) * 2048;
        #pragma unroll
        for (int i = 0; i < 8; ++i) {
            int e = base + t + 256 * i;
            if (e < N_EDGES) {
                int a0 = nbr[2 * e], a1 = nbr[2 * e + 1];
                bool m0 = (a0 & 7) == cls, m1 = (a1 & 7) == cls;
                if (m0 | m1) {
                    float dx = xyz[3 * a0]     - xyz[3 * a1];
                    float dy = xyz[3 * a0 + 1] - xyz[3 * a1 + 1];
                    float dz = xyz[3 * a0 + 2] - xyz[3 * a1 + 2];
                    float d = sqrtf(dx * dx + dy * dy + dz * dz);
                    float tv = fminf(d * TBL_SCALE, TBL_TMAX);
                    uint32 tq = (uint32)(tv * 32.0f + 0.5f);   // 11-bit idx + 5-bit frac
                    if (m1) {
                        int p1 = atomicAdd(&cnt[a1], 1);
                        if (p1 < CAP) inc32[((size_t)a1 << 6) | p1] = ((uint32)a0 << 16) | tq;
                    }
                    if (m0) {
                        int p0 = atomicAdd(&cnt[a0], 1);
                        if (p0 < CAP) inc32[((size_t)a0 << 6) | p0] = ((uint32)a1 << 16) | tq;
                    }
                }
            }
        }
    }
}

// ================= gather: r = embed[z], rf16 = bf16(G'[z]) =================
__global__ __launch_bounds__(256)
void k_gather(const int* __restrict__ z, const float* __restrict__ embed,
              const float* __restrict__ Gp, float* __restrict__ r,
              uint32* __restrict__ rf16) {
    int idx = blockIdx.x * 256 + threadIdx.x;
    if (idx >= N_PAD * 32) return;
    int n = idx >> 5, c4 = idx & 31;
    int zz = z[n < N_ATOMS ? n : 0];
    float4 v = *(const float4*)(embed + (size_t)zz * N_FEAT + c4 * 4);
    *(float4*)(r + (size_t)n * N_FEAT + c4 * 4) = v;
    float4 g = *(const float4*)(Gp + (size_t)zz * N_FEAT + c4 * 4);
    uint2 o;
    o.x = pack2f(g.x, g.y);
    o.y = pack2f(g.z, g.w);
    *(uint2*)(rf16 + (size_t)n * 64 + c4 * 2) = o;
}

// ================= gather aggregation (bucketed inc32) =================
__global__ __launch_bounds__(256)
void k_agg(const int* __restrict__ cnt, const uint32* __restrict__ inc32,
           const uint32* __restrict__ tblI, const uint32* __restrict__ rf,
           uint32* __restrict__ agg16) {
    int wv = threadIdx.x >> 6, lane = threadIdx.x & 63;
    int h = lane >> 5, lh = lane & 31;
    int n = blockIdx.x * 4 + wv;
    if (n >= N_ATOMS) return;
    int s = n << 6;
    int e = s + min(cnt[n], CAP);
    float a0 = 0.f, a1 = 0.f, a2 = 0.f, a3 = 0.f;
    int i = s;
    for (; i + 8 <= e; i += 8) {
        uint32 v[4];
        #pragma unroll
        for (int u = 0; u < 4; ++u) v[u] = inc32[i + 2 * u + h];
        int i0[4], oa[4];
        float fr[4];
        #pragma unroll
        for (int u = 0; u < 4; ++u) {
            oa[u] = v[u] >> 16;
            uint32 tq = v[u] & 0xffffu;
            i0[u] = tq >> 5;
            fr[u] = (float)(tq & 31u) * 0.03125f;
        }
        uint4 T[4];
        #pragma unroll
        for (int u = 0; u < 4; ++u) T[u] = *(const uint4*)(tblI + ((size_t)i0[u] * 64 + lh * 2) * 2);
        uint2 R[4];
        #pragma unroll
        for (int u = 0; u < 4; ++u) R[u] = *(const uint2*)(rf + (size_t)oa[u] * 64 + lh * 2);
        #pragma unroll
        for (int u = 0; u < 4; ++u) {
            float e0 = fmaf(fr[u], bf_lo(T[u].y) - bf_lo(T[u].x), bf_lo(T[u].x));
            float e1 = fmaf(fr[u], bf_hi(T[u].y) - bf_hi(T[u].x), bf_hi(T[u].x));
            float e2 = fmaf(fr[u], bf_lo(T[u].w) - bf_lo(T[u].z), bf_lo(T[u].z));
            float e3 = fmaf(fr[u], bf_hi(T[u].w) - bf_hi(T[u].z), bf_hi(T[u].z));
            a0 = fmaf(e0, bf_lo(R[u].x), a0);
            a1 = fmaf(e1, bf_hi(R[u].x), a1);
            a2 = fmaf(e2, bf_lo(R[u].y), a2);
            a3 = fmaf(e3, bf_hi(R[u].y), a3);
        }
    }
    for (; i < e; i += 2) {
        int idx = i + h;
        bool ok = idx < e;
        uint32 v = inc32[ok ? idx : s];
        int oa = v >> 16;
        uint32 tq = v & 0xffffu;
        int i0 = tq >> 5;
        float fr = (float)(tq & 31u) * 0.03125f;
        uint4 T = *(const uint4*)(tblI + ((size_t)i0 * 64 + lh * 2) * 2);
        uint2 R = *(const uint2*)(rf + (size_t)oa * 64 + lh * 2);
        float m = ok ? 1.0f : 0.0f;
        float e0 = fmaf(fr, bf_lo(T.y) - bf_lo(T.x), bf_lo(T.x));
        float e1 = fmaf(fr, bf_hi(T.y) - bf_hi(T.x), bf_hi(T.x));
        float e2 = fmaf(fr, bf_lo(T.w) - bf_lo(T.z), bf_lo(T.z));
        float e3 = fmaf(fr, bf_hi(T.w) - bf_hi(T.z), bf_hi(T.z));
        a0 = fmaf(e0, m * bf_lo(R.x), a0);
        a1 = fmaf(e1, m * bf_hi(R.x), a1);
        a2 = fmaf(e2, m * bf_lo(R.y), a2);
        a3 = fmaf(e3, m * bf_hi(R.y), a3);
    }
    a0 += __shfl_xor(a0, 32);
    a1 += __shfl_xor(a1, 32);
    a2 += __shfl_xor(a2, 32);
    a3 += __shfl_xor(a3, 32);
    if (h == 0) {
        uint2 o;
        o.x = pack2f(a0, a1);
        o.y = pack2f(a2, a3);
        *(uint2*)(agg16 + (size_t)n * 64 + lh * 2) = o;
    }
}

// ================= fused update (M=32, coalesced B-frag loads) =================
template <bool RO>
__global__ __launch_bounds__(256)
void k_update(const u16* __restrict__ agg16u,
              const float* __restrict__ bu1, const float* __restrict__ bu2,
              const u16* __restrict__ Wu1t, const u16* __restrict__ Wu2t,
              const u16* __restrict__ W3t, const float* __restrict__ b3,
              float* __restrict__ r, u16* __restrict__ rf16,
              const float* __restrict__ Wr2, const float* __restrict__ br2,
              const int* __restrict__ mol, float* __restrict__ out) {
    __shared__ u16 aT[32 * 136];
    __shared__ u16 hT[32 * 136];

    int tid = threadIdx.x;
    int w = tid >> 6, lane = tid & 63;
    int l15 = lane & 15, q = lane >> 4;
    int colbase = w * 32;
    size_t n0 = (size_t)blockIdx.x * 32;
    size_t fragoff = (size_t)(w * 2) * 512 + (size_t)lane * 8;

    bf16x8 bfr[4][2];
    #pragma unroll
    for (int kc = 0; kc < 4; ++kc)
        #pragma unroll
        for (int ntl = 0; ntl < 2; ++ntl)
            bfr[kc][ntl] = *(const bf16x8*)(Wu1t + kc * 4096 + ntl * 512 + fragoff);
    float rpre[2][2][4];
    #pragma unroll
    for (int ntl = 0; ntl < 2; ++ntl) {
        int col = colbase + ntl * 16 + l15;
        #pragma unroll
        for (int m = 0; m < 2; ++m)
            #pragma unroll
            for (int reg = 0; reg < 4; ++reg)
                rpre[ntl][m][reg] = r[(n0 + m * 16 + q * 4 + reg) * N_FEAT + col];
    }

    #pragma unroll
    for (int i = 0; i < 2; ++i) {
        int idx = tid + 256 * i;
        int row = idx >> 4, c = idx & 15;
        uint4 v = *(const uint4*)(agg16u + (n0 + row) * 128 + c * 8);
        *(uint4*)&aT[row * 136 + c * 8] = v;
    }
    __syncthreads();

    f32x4 acc[2][2];

    // GEMM1
    #pragma unroll
    for (int m = 0; m < 2; ++m)
        #pragma unroll
        for (int ntl = 0; ntl < 2; ++ntl) acc[m][ntl] = (f32x4){0.f, 0.f, 0.f, 0.f};
    #pragma unroll
    for (int kc = 0; kc < 4; ++kc)
        #pragma unroll
        for (int m = 0; m < 2; ++m) {
            bf16x8 a = *(const bf16x8*)(aT + (m * 16 + l15) * 136 + kc * 32 + q * 8);
            acc[m][0] = __builtin_amdgcn_mfma_f32_16x16x32_bf16(a, bfr[kc][0], acc[m][0], 0, 0, 0);
            acc[m][1] = __builtin_amdgcn_mfma_f32_16x16x32_bf16(a, bfr[kc][1], acc[m][1], 0, 0, 0);
        }
    #pragma unroll
    for (int ntl = 0; ntl < 2; ++ntl) {
        int col = colbase + ntl * 16 + l15;
        float bv = bu1[col];
        #pragma unroll
        for (int m = 0; m < 2; ++m)
            #pragma unroll
            for (int reg = 0; reg < 4; ++reg)
                hT[(m * 16 + q * 4 + reg) * 136 + col] = (u16)f2bf_u(ssp_f(acc[m][ntl][reg] + bv));
    }
    __syncthreads();

    // GEMM2
    #pragma unroll
    for (int kc = 0; kc < 4; ++kc)
        #pragma unroll
        for (int ntl = 0; ntl < 2; ++ntl)
            bfr[kc][ntl] = *(const bf16x8*)(Wu2t + kc * 4096 + ntl * 512 + fragoff);
    #pragma unroll
    for (int m = 0; m < 2; ++m)
        #pragma unroll
        for (int ntl = 0; ntl < 2; ++ntl) acc[m][ntl] = (f32x4){0.f, 0.f, 0.f, 0.f};
    #pragma unroll
    for (int kc = 0; kc < 4; ++kc)
        #pragma unroll
        for (int m = 0; m < 2; ++m) {
            bf16x8 a = *(const bf16x8*)(hT + (m * 16 + l15) * 136 + kc * 32 + q * 8);
            acc[m][0] = __builtin_amdgcn_mfma_f32_16x16x32_bf16(a, bfr[kc][0], acc[m][0], 0, 0, 0);
            acc[m][1] = __builtin_amdgcn_mfma_f32_16x16x32_bf16(a, bfr[kc][1], acc[m][1], 0, 0, 0);
        }
    __syncthreads();
    #pragma unroll
    for (int ntl = 0; ntl < 2; ++ntl) {
        int col = colbase + ntl * 16 + l15;
        float bv = bu2[col];
        #pragma unroll
        for (int m = 0; m < 2; ++m)
            #pragma unroll
            for (int reg = 0; reg < 4; ++reg) {
                int row = m * 16 + q * 4 + reg;
                float v = acc[m][ntl][reg] + bv + rpre[ntl][m][reg];
                if (!RO) r[(n0 + row) * N_FEAT + col] = v;
                aT[row * 136 + col] = (u16)f2bf_u(v);
            }
    }
    __syncthreads();

    // GEMM3
    #pragma unroll
    for (int kc = 0; kc < 4; ++kc)
        #pragma unroll
        for (int ntl = 0; ntl < 2; ++ntl)
            bfr[kc][ntl] = *(const bf16x8*)(W3t + kc * 4096 + ntl * 512 + fragoff);
    #pragma unroll
    for (int m = 0; m < 2; ++m)
        #pragma unroll
        for (int ntl = 0; ntl < 2; ++ntl) acc[m][ntl] = (f32x4){0.f, 0.f, 0.f, 0.f};
    #pragma unroll
    for (int kc = 0; kc < 4; ++kc)
        #pragma unroll
        for (int m = 0; m < 2; ++m) {
            bf16x8 a = *(const bf16x8*)(aT + (m * 16 + l15) * 136 + kc * 32 + q * 8);
            acc[m][0] = __builtin_amdgcn_mfma_f32_16x16x32_bf16(a, bfr[kc][0], acc[m][0], 0, 0, 0);
            acc[m][1] = __builtin_amdgcn_mfma_f32_16x16x32_bf16(a, bfr[kc][1], acc[m][1], 0, 0, 0);
        }

    if (!RO) {
        #pragma unroll
        for (int ntl = 0; ntl < 2; ++ntl) {
            int col = colbase + ntl * 16 + l15;
            float bv = b3[col];
            #pragma unroll
            for (int m = 0; m < 2; ++m)
                #pragma unroll
                for (int reg = 0; reg < 4; ++reg) {
                    int row = m * 16 + q * 4 + reg;
                    rf16[(n0 + row) * N_FEAT + col] = (u16)f2bf_u(acc[m][ntl][reg] + bv);
                }
        }
    } else {
        float (*red)[4][17] = (float(*)[4][17])aT;
        __syncthreads();
        float b1v[2], w2v[2];
        #pragma unroll
        for (int ntl = 0; ntl < 2; ++ntl) {
            int col = colbase + ntl * 16 + l15;
            b1v[ntl] = b3[col];
            w2v[ntl] = Wr2[col];
        }
        #pragma unroll
        for (int m = 0; m < 2; ++m)
            #pragma unroll
            for (int reg = 0; reg < 4; ++reg) {
                float pk = ssp_f(acc[m][0][reg] + b1v[0]) * w2v[0]
                         + ssp_f(acc[m][1][reg] + b1v[1]) * w2v[1];
                red[m * 16 + q * 4 + reg][w][l15] = pk;
            }
        __syncthreads();
        if (tid < 64) {
            int row = tid & 31, key = tid >> 5;
            int atom = (int)n0 + row;
            if (atom < N_ATOMS) {
                float s = br2[key];
                #pragma unroll
                for (int j = 0; j < 16; ++j)
                    s += red[row][2 * key][j] + red[row][2 * key + 1][j];
                atomicAdd(&out[mol[atom] * 2 + key], s);
            }
        }
    }
}

// ================= host launcher =================
extern "C" void kernel_launch(void* const* d_in, const int* in_sizes, int n_in,
                              void* d_out, int out_size, void* d_ws, size_t ws_size,
                              hipStream_t stream) {
    const int*   z     = (const int*)d_in[0];
    const float* xyz   = (const float*)d_in[1];
    const int*   nbr   = (const int*)d_in[2];
    const int*   mol   = (const int*)d_in[3];
    const float* embed = (const float*)d_in[4];
    const float* We1   = (const float*)d_in[5];
    const float* be1   = (const float*)d_in[6];
    const float* We2   = (const float*)d_in[7];
    const float* be2   = (const float*)d_in[8];
    const float* Wn    = (const float*)d_in[9];
    const float* bn    = (const float*)d_in[10];
    const float* Wu1   = (const float*)d_in[11];
    const float* bu1   = (const float*)d_in[12];
    const float* Wu2   = (const float*)d_in[13];
    const float* bu2   = (const float*)d_in[14];
    const float* Wr1   = (const float*)d_in[15];
    const float* br1   = (const float*)d_in[16];
    const float* Wr2   = (const float*)d_in[17];
    const float* br2   = (const float*)d_in[18];
    float* out = (float*)d_out;

    float* ws = (float*)d_ws;
    const size_t NRP = (size_t)N_PAD * N_FEAT;
    const size_t NHP = (size_t)N_PAD * 64;
    float*  r_buf  = ws;
    uint32* agg16  = (uint32*)(ws + NRP);
    uint32* rf16   = agg16 + NHP;
    int*    cnt    = (int*)(rf16 + NHP);
    uint32* inc32  = (uint32*)(cnt + 50048);
    uint32* tblI   = inc32 + (size_t)N_ATOMS * CAP;
    u16*    Wt     = (u16*)(tblI + (size_t)3 * TBL_N * 128);
    float*  Gp     = (float*)(Wt + 10 * 16384);

    hipMemsetAsync(d_out, 0, (size_t)out_size * sizeof(float), stream);
    hipMemsetAsync(cnt, 0, 50000 * sizeof(int), stream);

    k_uberA<<<FILL_START + NB_EDGE, 256, 0, stream>>>(
        nbr, xyz, cnt, inc32, We1, be1, We2, be2, tblI,
        Wn, bn, Wu1, Wu2, Wr1, Wt, embed, Gp);

    k_gather<<<(N_PAD * 32) / 256, 256, 0, stream>>>(z, embed, Gp, r_buf, rf16);

    const int GA2 = N_PAD / 32;   // 1564
    for (int l = 0; l < N_CONV; ++l) {
        k_agg<<<(N_ATOMS + 3) / 4, 256, 0, stream>>>(cnt, inc32,
                                                     tblI + (size_t)l * TBL_N * 128,
                                                     rf16, agg16);
        const u16* Wu1t = Wt + (size_t)(3 + l) * 16384;
        const u16* Wu2t = Wt + (size_t)(6 + l) * 16384;
        if (l < N_CONV - 1) {
            k_update<false><<<GA2, 256, 0, stream>>>((const u16*)agg16, bu1 + l * 128,
                                                     bu2 + l * 128, Wu1t, Wu2t,
                                                     Wt + (size_t)(l + 1) * 16384,
                                                     bn + (l + 1) * 128,
                                                     r_buf, (u16*)rf16, Wr2, br2, mol, out);
        } else {
            k_update<true><<<GA2, 256, 0, stream>>>((const u16*)agg16, bu1 + l * 128,
                                                    bu2 + l * 128, Wu1t, Wu2t,
                                                    Wt + (size_t)9 * 16384, br1,
                                                    r_buf, (u16*)rf16, Wr2, br2, mol, out);
        }
    }
}

// Round 16
// 405.005 us; speedup vs baseline: 1.2435x; 1.0181x over previous
//
#include <hip/hip_runtime.h>
#include <math.h>

#define N_ATOMS   50000
#define N_PAD     50048
#define N_EDGES   600000
#define N_FEAT    128
#define N_GAUSS   32
#define N_CONV    3
#define N_MOLS    1000
#define HIDDEN_RO 64
#define CAP       64

#define TBL_N     1921           // rows per layer, d = i/256, covers [0, 7.5]
#define TBL_BPL   31
#define TBL_SCALE 256.0f
#define TBL_TMAX  1919.0f
#define NB_EDGE   2344           // 293 chunks x 8 classes
#define NB_BUILD  (N_CONV * TBL_BPL)   // 93
#define NB_WPREP  40
#define NB_GATH   6256           // N_PAD*32/256
#define BUILD_START NB_EDGE                      // 2344
#define WPREP_START (NB_EDGE + NB_BUILD)         // 2437
#define GATH_START  (NB_EDGE + NB_BUILD + NB_WPREP)  // 2477

typedef unsigned int   uint32;
typedef unsigned short u16;
typedef __attribute__((ext_vector_type(8))) short bf16x8;
typedef __attribute__((ext_vector_type(4))) float f32x4;

__device__ __forceinline__ float ssp_f(float x) {
    float e = __expf(-fabsf(x));
    return fmaxf(x, 0.0f) + __logf(1.0f + e) - 0.6931471805599453f;
}
__device__ __forceinline__ uint32 f2bf_u(float x) {
    uint32 u = __float_as_uint(x);
    return (u + 0x7fffu + ((u >> 16) & 1u)) >> 16;
}
__device__ __forceinline__ uint32 pack2f(float a, float b) {
    return f2bf_u(a) | (f2bf_u(b) << 16);
}
__device__ __forceinline__ float bf_lo(uint32 u) { return __uint_as_float(u << 16); }
__device__ __forceinline__ float bf_hi(uint32 u) { return __uint_as_float(u & 0xffff0000u); }

// ================= pre: Gp = embed@Wn0+bn0 | zero cnt | zero out =================
__global__ __launch_bounds__(256)
void k_pre(const float* __restrict__ embed, const float* __restrict__ Wn,
           const float* __restrict__ bn, float* __restrict__ Gp,
           int* __restrict__ cnt, float* __restrict__ out, int out_size) {
    int b = blockIdx.x, t = threadIdx.x;
    if (b < 7) {
        int row = b * 16 + (t >> 4);
        int tf = t & 15;
        if (row < 100) {
            float acc[8];
            #pragma unroll
            for (int j = 0; j < 8; ++j) acc[j] = 0.0f;
            for (int k = 0; k < N_FEAT; ++k) {
                float a = embed[row * N_FEAT + k];
                float4 w0 = *(const float4*)(Wn + k * N_FEAT + tf * 8);
                float4 w1 = *(const float4*)(Wn + k * N_FEAT + tf * 8 + 4);
                acc[0] += a * w0.x; acc[1] += a * w0.y;
                acc[2] += a * w0.z; acc[3] += a * w0.w;
                acc[4] += a * w1.x; acc[5] += a * w1.y;
                acc[6] += a * w1.z; acc[7] += a * w1.w;
            }
            #pragma unroll
            for (int j = 0; j < 8; ++j)
                Gp[row * N_FEAT + tf * 8 + j] = acc[j] + bn[tf * 8 + j];
        }
    } else if (b < 56) {
        int i = (b - 7) * 1024 + t * 4;
        if (i < 50048) *(int4*)(cnt + i) = make_int4(0, 0, 0, 0);
    } else {
        for (int j = t; j < out_size; j += 256) out[j] = 0.0f;
    }
}

// ================= uber-A: fill | build | wprep | gather =================
__global__ __launch_bounds__(256)
void k_uberA(const int* __restrict__ nbr, const float* __restrict__ xyz,
             int* __restrict__ cnt, uint32* __restrict__ inc32,
             const float* __restrict__ We1_all, const float* __restrict__ be1_all,
             const float* __restrict__ We2_all, const float* __restrict__ be2_all,
             uint32* __restrict__ tblI,
             const float* __restrict__ Wn,
             const float* __restrict__ Wu1,
             const float* __restrict__ Wu2, const float* __restrict__ Wr1,
             u16* __restrict__ Wt,
             const int* __restrict__ z, const float* __restrict__ embed,
             const float* __restrict__ Gp, float* __restrict__ r,
             uint32* __restrict__ rf16) {
    __shared__ float smemA[17408 / 4];
    int b = blockIdx.x;
    int t = threadIdx.x;

    if (b < NB_EDGE) {
        // ---- dist + fill, XCD-class partitioned (b&7 tracks round-robin XCD) ----
        int cls = b & 7;
        int base = (b >> 3) * 2048;
        #pragma unroll
        for (int i = 0; i < 8; ++i) {
            int e = base + t + 256 * i;
            if (e < N_EDGES) {
                int a0 = nbr[2 * e], a1 = nbr[2 * e + 1];
                bool m0 = (a0 & 7) == cls, m1 = (a1 & 7) == cls;
                if (m0 | m1) {
                    float dx = xyz[3 * a0]     - xyz[3 * a1];
                    float dy = xyz[3 * a0 + 1] - xyz[3 * a1 + 1];
                    float dz = xyz[3 * a0 + 2] - xyz[3 * a1 + 2];
                    float d = sqrtf(dx * dx + dy * dy + dz * dz);
                    float tv = fminf(d * TBL_SCALE, TBL_TMAX);
                    uint32 tq = (uint32)(tv * 32.0f + 0.5f);   // 11-bit idx + 5-bit frac
                    if (m1) {
                        int p1 = atomicAdd(&cnt[a1], 1);
                        if (p1 < CAP) inc32[((size_t)a1 << 6) | p1] = ((uint32)a0 << 16) | tq;
                    }
                    if (m0) {
                        int p0 = atomicAdd(&cnt[a0], 1);
                        if (p0 < CAP) inc32[((size_t)a0 << 6) | p0] = ((uint32)a1 << 16) | tq;
                    }
                }
            }
        }
        return;
    }
    if (b < WPREP_START) {
        // ---- edge-MLP table build ----
        int bb   = b - BUILD_START;
        int l    = bb / TBL_BPL;
        int row0 = (bb % TBL_BPL) * 64;
        const float* We1 = We1_all + (size_t)l * N_GAUSS * N_FEAT;
        const float* be1 = be1_all + (size_t)l * N_FEAT;
        const float* We2 = We2_all + (size_t)l * N_FEAT * N_FEAT;
        const float* be2 = be2_all + (size_t)l * N_FEAT;
        uint32* tl = tblI + (size_t)l * TBL_N * 128;
        u16* h1T = (u16*)smemA;          // [128][68]

        const float width = 5.0f / 31.0f;
        const float coef = -0.5f / (width * width);

        int tf = t & 15, te = t >> 4;
        int f0 = tf * 8, eb = te * 4;
        float dloc[4];
        #pragma unroll
        for (int i = 0; i < 4; ++i) dloc[i] = (float)(row0 + eb + i) * (1.0f / TBL_SCALE);

        float acc[4][8];
        #pragma unroll
        for (int i = 0; i < 4; ++i)
            #pragma unroll
            for (int j = 0; j < 8; ++j) acc[i][j] = 0.0f;

        for (int g = 0; g < N_GAUSS; ++g) {
            float mu = (float)g * width;
            float av[4];
            #pragma unroll
            for (int i = 0; i < 4; ++i) {
                float diff = dloc[i] - mu;
                av[i] = __expf(coef * diff * diff);
            }
            float4 w0 = *(const float4*)(We1 + g * N_FEAT + f0);
            float4 w1 = *(const float4*)(We1 + g * N_FEAT + f0 + 4);
            float wv[8] = {w0.x, w0.y, w0.z, w0.w, w1.x, w1.y, w1.z, w1.w};
            #pragma unroll
            for (int i = 0; i < 4; ++i)
                #pragma unroll
                for (int j = 0; j < 8; ++j) acc[i][j] += av[i] * wv[j];
        }
        #pragma unroll
        for (int j = 0; j < 8; ++j) {
            float bb2 = be1[f0 + j];
            uint2 hv;
            hv.x = pack2f(ssp_f(acc[0][j] + bb2), ssp_f(acc[1][j] + bb2));
            hv.y = pack2f(ssp_f(acc[2][j] + bb2), ssp_f(acc[3][j] + bb2));
            *(uint2*)&h1T[(f0 + j) * 68 + eb] = hv;
        }
        __syncthreads();

        #pragma unroll
        for (int i = 0; i < 4; ++i)
            #pragma unroll
            for (int j = 0; j < 8; ++j) acc[i][j] = 0.0f;
        #pragma unroll 2
        for (int c = 0; c < N_FEAT; ++c) {
            uint2 hv = *(const uint2*)&h1T[c * 68 + eb];
            float av[4] = {bf_lo(hv.x), bf_hi(hv.x), bf_lo(hv.y), bf_hi(hv.y)};
            float4 w0 = *(const float4*)(We2 + c * N_FEAT + f0);
            float4 w1 = *(const float4*)(We2 + c * N_FEAT + f0 + 4);
            float wv[8] = {w0.x, w0.y, w0.z, w0.w, w1.x, w1.y, w1.z, w1.w};
            #pragma unroll
            for (int i = 0; i < 4; ++i)
                #pragma unroll
                for (int j = 0; j < 8; ++j) acc[i][j] += av[i] * wv[j];
        }
        __syncthreads();

        uint32* pvS = (uint32*)smemA;   // [64][65]
        #pragma unroll
        for (int i = 0; i < 4; ++i)
            #pragma unroll
            for (int p = 0; p < 4; ++p)
                pvS[(eb + i) * 65 + tf * 4 + p] =
                    pack2f(acc[i][2 * p]     + be2[f0 + 2 * p],
                           acc[i][2 * p + 1] + be2[f0 + 2 * p + 1]);
        __syncthreads();

        #pragma unroll
        for (int i = 0; i < 16; ++i) {
            int idx = t + 256 * i;
            int e = idx >> 6, fp = idx & 63;
            int ent = row0 + e;
            if (ent < TBL_N - 1) {
                if (e < 63) {
                    uint2 v2;
                    v2.x = pvS[e * 65 + fp];
                    v2.y = pvS[(e + 1) * 65 + fp];
                    *(uint2*)(tl + ((size_t)ent * 64 + fp) * 2) = v2;
                } else {
                    tl[((size_t)ent * 64 + fp) * 2] = pvS[63 * 65 + fp];
                }
            }
        }
        if (row0 > 0 && t < 64)
            tl[((size_t)(row0 - 1) * 64 + t) * 2 + 1] = pvS[t];
        return;
    }
    if (b < GATH_START) {
        // ---- weight prep -> fragment-coalesced layout ----
        int wb = b - WPREP_START;
        int gid = wb * 256 + t;
        #pragma unroll
        for (int i = 0; i < 16; ++i) {
            int idx = gid + i * (NB_WPREP * 256);
            int j    = idx & 7;
            int lane = (idx >> 3) & 63;
            int cg   = (idx >> 9) & 7;
            int kc   = (idx >> 12) & 3;
            int mat  = idx >> 14;
            int col  = cg * 16 + (lane & 15);
            int k    = kc * 32 + (lane >> 4) * 8 + j;
            float v;
            if (mat < 3)      v = Wn [(size_t)mat * 16384 + k * 128 + col];
            else if (mat < 6) v = Wu1[(size_t)(mat - 3) * 16384 + k * 128 + col];
            else if (mat < 9) v = Wu2[(size_t)(mat - 6) * 16384 + k * 128 + col];
            else { int key = col >> 6, h = col & 63; v = Wr1[(size_t)key * 128 * 64 + k * 64 + h]; }
            Wt[(size_t)idx] = (u16)f2bf_u(v);
        }
        return;
    }
    // ---- gather: r = embed[z], rf16 = bf16(G'[z]) ----
    {
        int idx = (b - GATH_START) * 256 + t;
        int n = idx >> 5, c4 = idx & 31;
        int zz = z[n < N_ATOMS ? n : 0];
        float4 v = *(const float4*)(embed + (size_t)zz * N_FEAT + c4 * 4);
        *(float4*)(r + (size_t)n * N_FEAT + c4 * 4) = v;
        float4 g = *(const float4*)(Gp + (size_t)zz * N_FEAT + c4 * 4);
        uint2 o;
        o.x = pack2f(g.x, g.y);
        o.y = pack2f(g.z, g.w);
        *(uint2*)(rf16 + (size_t)n * 64 + c4 * 2) = o;
    }
}

// ================= gather aggregation (coalesced bucket load + shfl) =================
__global__ __launch_bounds__(256)
void k_agg(const int* __restrict__ cnt, const uint32* __restrict__ inc32,
           const uint32* __restrict__ tblI, const uint32* __restrict__ rf,
           uint32* __restrict__ agg16) {
    int wv = threadIdx.x >> 6, lane = threadIdx.x & 63;
    int h = lane >> 5, lh = lane & 31;
    int n = blockIdx.x * 4 + wv;
    if (n >= N_ATOMS) return;
    int s = n << 6;
    int c = min(cnt[n], CAP);
    uint32 vAll = inc32[s + lane];       // whole bucket, one coalesced wave load
    float a0 = 0.f, a1 = 0.f, a2 = 0.f, a3 = 0.f;
    int i = 0;
    for (; i + 8 <= c; i += 8) {
        uint32 v[4];
        #pragma unroll
        for (int u = 0; u < 4; ++u) v[u] = __shfl(vAll, i + 2 * u + h);
        int i0[4], oa[4];
        float fr[4];
        #pragma unroll
        for (int u = 0; u < 4; ++u) {
            oa[u] = v[u] >> 16;
            uint32 tq = v[u] & 0xffffu;
            i0[u] = tq >> 5;
            fr[u] = (float)(tq & 31u) * 0.03125f;
        }
        uint4 T[4];
        #pragma unroll
        for (int u = 0; u < 4; ++u) T[u] = *(const uint4*)(tblI + ((size_t)i0[u] * 64 + lh * 2) * 2);
        uint2 R[4];
        #pragma unroll
        for (int u = 0; u < 4; ++u) R[u] = *(const uint2*)(rf + (size_t)oa[u] * 64 + lh * 2);
        #pragma unroll
        for (int u = 0; u < 4; ++u) {
            float e0 = fmaf(fr[u], bf_lo(T[u].y) - bf_lo(T[u].x), bf_lo(T[u].x));
            float e1 = fmaf(fr[u], bf_hi(T[u].y) - bf_hi(T[u].x), bf_hi(T[u].x));
            float e2 = fmaf(fr[u], bf_lo(T[u].w) - bf_lo(T[u].z), bf_lo(T[u].z));
            float e3 = fmaf(fr[u], bf_hi(T[u].w) - bf_hi(T[u].z), bf_hi(T[u].z));
            a0 = fmaf(e0, bf_lo(R[u].x), a0);
            a1 = fmaf(e1, bf_hi(R[u].x), a1);
            a2 = fmaf(e2, bf_lo(R[u].y), a2);
            a3 = fmaf(e3, bf_hi(R[u].y), a3);
        }
    }
    for (; i < c; i += 2) {
        int src = i + h;
        bool ok = src < c;
        uint32 v = __shfl(vAll, ok ? src : 0);
        int oa = v >> 16;
        uint32 tq = v & 0xffffu;
        int i0 = tq >> 5;
        float fr = (float)(tq & 31u) * 0.03125f;
        uint4 T = *(const uint4*)(tblI + ((size_t)i0 * 64 + lh * 2) * 2);
        uint2 R = *(const uint2*)(rf + (size_t)oa * 64 + lh * 2);
        float m = ok ? 1.0f : 0.0f;
        float e0 = fmaf(fr, bf_lo(T.y) - bf_lo(T.x), bf_lo(T.x));
        float e1 = fmaf(fr, bf_hi(T.y) - bf_hi(T.x), bf_hi(T.x));
        float e2 = fmaf(fr, bf_lo(T.w) - bf_lo(T.z), bf_lo(T.z));
        float e3 = fmaf(fr, bf_hi(T.w) - bf_hi(T.z), bf_hi(T.z));
        a0 = fmaf(e0, m * bf_lo(R.x), a0);
        a1 = fmaf(e1, m * bf_hi(R.x), a1);
        a2 = fmaf(e2, m * bf_lo(R.y), a2);
        a3 = fmaf(e3, m * bf_hi(R.y), a3);
    }
    a0 += __shfl_xor(a0, 32);
    a1 += __shfl_xor(a1, 32);
    a2 += __shfl_xor(a2, 32);
    a3 += __shfl_xor(a3, 32);
    if (h == 0) {
        uint2 o;
        o.x = pack2f(a0, a1);
        o.y = pack2f(a2, a3);
        *(uint2*)(agg16 + (size_t)n * 64 + lh * 2) = o;
    }
}

// ================= fused update (M=32, coalesced B-frag loads) =================
template <bool RO>
__global__ __launch_bounds__(256)
void k_update(const u16* __restrict__ agg16u,
              const float* __restrict__ bu1, const float* __restrict__ bu2,
              const u16* __restrict__ Wu1t, const u16* __restrict__ Wu2t,
              const u16* __restrict__ W3t, const float* __restrict__ b3,
              float* __restrict__ r, u16* __restrict__ rf16,
              const float* __restrict__ Wr2, const float* __restrict__ br2,
              const int* __restrict__ mol, float* __restrict__ out) {
    __shared__ u16 aT[32 * 136];
    __shared__ u16 hT[32 * 136];

    int tid = threadIdx.x;
    int w = tid >> 6, lane = tid & 63;
    int l15 = lane & 15, q = lane >> 4;
    int colbase = w * 32;
    size_t n0 = (size_t)blockIdx.x * 32;
    size_t fragoff = (size_t)(w * 2) * 512 + (size_t)lane * 8;

    bf16x8 bfr[4][2];
    #pragma unroll
    for (int kc = 0; kc < 4; ++kc)
        #pragma unroll
        for (int ntl = 0; ntl < 2; ++ntl)
            bfr[kc][ntl] = *(const bf16x8*)(Wu1t + kc * 4096 + ntl * 512 + fragoff);
    float rpre[2][2][4];
    #pragma unroll
    for (int ntl = 0; ntl < 2; ++ntl) {
        int col = colbase + ntl * 16 + l15;
        #pragma unroll
        for (int m = 0; m < 2; ++m)
            #pragma unroll
            for (int reg = 0; reg < 4; ++reg)
                rpre[ntl][m][reg] = r[(n0 + m * 16 + q * 4 + reg) * N_FEAT + col];
    }

    #pragma unroll
    for (int i = 0; i < 2; ++i) {
        int idx = tid + 256 * i;
        int row = idx >> 4, c = idx & 15;
        uint4 v = *(const uint4*)(agg16u + (n0 + row) * 128 + c * 8);
        *(uint4*)&aT[row * 136 + c * 8] = v;
    }
    __syncthreads();

    f32x4 acc[2][2];

    // GEMM1
    #pragma unroll
    for (int m = 0; m < 2; ++m)
        #pragma unroll
        for (int ntl = 0; ntl < 2; ++ntl) acc[m][ntl] = (f32x4){0.f, 0.f, 0.f, 0.f};
    #pragma unroll
    for (int kc = 0; kc < 4; ++kc)
        #pragma unroll
        for (int m = 0; m < 2; ++m) {
            bf16x8 a = *(const bf16x8*)(aT + (m * 16 + l15) * 136 + kc * 32 + q * 8);
            acc[m][0] = __builtin_amdgcn_mfma_f32_16x16x32_bf16(a, bfr[kc][0], acc[m][0], 0, 0, 0);
            acc[m][1] = __builtin_amdgcn_mfma_f32_16x16x32_bf16(a, bfr[kc][1], acc[m][1], 0, 0, 0);
        }
    #pragma unroll
    for (int ntl = 0; ntl < 2; ++ntl) {
        int col = colbase + ntl * 16 + l15;
        float bv = bu1[col];
        #pragma unroll
        for (int m = 0; m < 2; ++m)
            #pragma unroll
            for (int reg = 0; reg < 4; ++reg)
                hT[(m * 16 + q * 4 + reg) * 136 + col] = (u16)f2bf_u(ssp_f(acc[m][ntl][reg] + bv));
    }
    __syncthreads();

    // GEMM2
    #pragma unroll
    for (int kc = 0; kc < 4; ++kc)
        #pragma unroll
        for (int ntl = 0; ntl < 2; ++ntl)
            bfr[kc][ntl] = *(const bf16x8*)(Wu2t + kc * 4096 + ntl * 512 + fragoff);
    #pragma unroll
    for (int m = 0; m < 2; ++m)
        #pragma unroll
        for (int ntl = 0; ntl < 2; ++ntl) acc[m][ntl] = (f32x4){0.f, 0.f, 0.f, 0.f};
    #pragma unroll
    for (int kc = 0; kc < 4; ++kc)
        #pragma unroll
        for (int m = 0; m < 2; ++m) {
            bf16x8 a = *(const bf16x8*)(hT + (m * 16 + l15) * 136 + kc * 32 + q * 8);
            acc[m][0] = __builtin_amdgcn_mfma_f32_16x16x32_bf16(a, bfr[kc][0], acc[m][0], 0, 0, 0);
            acc[m][1] = __builtin_amdgcn_mfma_f32_16x16x32_bf16(a, bfr[kc][1], acc[m][1], 0, 0, 0);
        }
    __syncthreads();
    #pragma unroll
    for (int ntl = 0; ntl < 2; ++ntl) {
        int col = colbase + ntl * 16 + l15;
        float bv = bu2[col];
        #pragma unroll
        for (int m = 0; m < 2; ++m)
            #pragma unroll
            for (int reg = 0; reg < 4; ++reg) {
                int row = m * 16 + q * 4 + reg;
                float v = acc[m][ntl][reg] + bv + rpre[ntl][m][reg];
                if (!RO) r[(n0 + row) * N_FEAT + col] = v;
                aT[row * 136 + col] = (u16)f2bf_u(v);
            }
    }
    __syncthreads();

    // GEMM3
    #pragma unroll
    for (int kc = 0; kc < 4; ++kc)
        #pragma unroll
        for (int ntl = 0; ntl < 2; ++ntl)
            bfr[kc][ntl] = *(const bf16x8*)(W3t + kc * 4096 + ntl * 512 + fragoff);
    #pragma unroll
    for (int m = 0; m < 2; ++m)
        #pragma unroll
        for (int ntl = 0; ntl < 2; ++ntl) acc[m][ntl] = (f32x4){0.f, 0.f, 0.f, 0.f};
    #pragma unroll
    for (int kc = 0; kc < 4; ++kc)
        #pragma unroll
        for (int m = 0; m < 2; ++m) {
            bf16x8 a = *(const bf16x8*)(aT + (m * 16 + l15) * 136 + kc * 32 + q * 8);
            acc[m][0] = __builtin_amdgcn_mfma_f32_16x16x32_bf16(a, bfr[kc][0], acc[m][0], 0, 0, 0);
            acc[m][1] = __builtin_amdgcn_mfma_f32_16x16x32_bf16(a, bfr[kc][1], acc[m][1], 0, 0, 0);
        }

    if (!RO) {
        #pragma unroll
        for (int ntl = 0; ntl < 2; ++ntl) {
            int col = colbase + ntl * 16 + l15;
            float bv = b3[col];
            #pragma unroll
            for (int m = 0; m < 2; ++m)
                #pragma unroll
                for (int reg = 0; reg < 4; ++reg) {
                    int row = m * 16 + q * 4 + reg;
                    rf16[(n0 + row) * N_FEAT + col] = (u16)f2bf_u(acc[m][ntl][reg] + bv);
                }
        }
    } else {
        float (*red)[4][17] = (float(*)[4][17])aT;
        __syncthreads();
        float b1v[2], w2v[2];
        #pragma unroll
        for (int ntl = 0; ntl < 2; ++ntl) {
            int col = colbase + ntl * 16 + l15;
            b1v[ntl] = b3[col];
            w2v[ntl] = Wr2[col];
        }
        #pragma unroll
        for (int m = 0; m < 2; ++m)
            #pragma unroll
            for (int reg = 0; reg < 4; ++reg) {
                float pk = ssp_f(acc[m][0][reg] + b1v[0]) * w2v[0]
                         + ssp_f(acc[m][1][reg] + b1v[1]) * w2v[1];
                red[m * 16 + q * 4 + reg][w][l15] = pk;
            }
        __syncthreads();
        if (tid < 64) {
            int row = tid & 31, key = tid >> 5;
            int atom = (int)n0 + row;
            if (atom < N_ATOMS) {
                float s = br2[key];
                #pragma unroll
                for (int j = 0; j < 16; ++j)
                    s += red[row][2 * key][j] + red[row][2 * key + 1][j];
                atomicAdd(&out[mol[atom] * 2 + key], s);
            }
        }
    }
}

// ================= host launcher =================
extern "C" void kernel_launch(void* const* d_in, const int* in_sizes, int n_in,
                              void* d_out, int out_size, void* d_ws, size_t ws_size,
                              hipStream_t stream) {
    const int*   z     = (const int*)d_in[0];
    const float* xyz   = (const float*)d_in[1];
    const int*   nbr   = (const int*)d_in[2];
    const int*   mol   = (const int*)d_in[3];
    const float* embed = (const float*)d_in[4];
    const float* We1   = (const float*)d_in[5];
    const float* be1   = (const float*)d_in[6];
    const float* We2   = (const float*)d_in[7];
    const float* be2   = (const float*)d_in[8];
    const float* Wn    = (const float*)d_in[9];
    const float* bn    = (const float*)d_in[10];
    const float* Wu1   = (const float*)d_in[11];
    const float* bu1   = (const float*)d_in[12];
    const float* Wu2   = (const float*)d_in[13];
    const float* bu2   = (const float*)d_in[14];
    const float* Wr1   = (const float*)d_in[15];
    const float* br1   = (const float*)d_in[16];
    const float* Wr2   = (const float*)d_in[17];
    const float* br2   = (const float*)d_in[18];
    float* out = (float*)d_out;

    float* ws = (float*)d_ws;
    const size_t NRP = (size_t)N_PAD * N_FEAT;
    const size_t NHP = (size_t)N_PAD * 64;
    float*  r_buf  = ws;
    uint32* agg16  = (uint32*)(ws + NRP);
    uint32* rf16   = agg16 + NHP;
    int*    cnt    = (int*)(rf16 + NHP);
    uint32* inc32  = (uint32*)(cnt + 50048);
    uint32* tblI   = inc32 + (size_t)N_ATOMS * CAP;
    u16*    Wt     = (u16*)(tblI + (size_t)3 * TBL_N * 128);
    float*  Gp     = (float*)(Wt + 10 * 16384);

    k_pre<<<57, 256, 0, stream>>>(embed, Wn, bn, Gp, cnt, out, out_size);

    k_uberA<<<GATH_START + NB_GATH, 256, 0, stream>>>(
        nbr, xyz, cnt, inc32, We1, be1, We2, be2, tblI,
        Wn, Wu1, Wu2, Wr1, Wt, z, embed, Gp, r_buf, rf16);

    const int GA2 = N_PAD / 32;   // 1564
    for (int l = 0; l < N_CONV; ++l) {
        k_agg<<<(N_ATOMS + 3) / 4, 256, 0, stream>>>(cnt, inc32,
                                                     tblI + (size_t)l * TBL_N * 128,
                                                     rf16, agg16);
        const u16* Wu1t = Wt + (size_t)(3 + l) * 16384;
        const u16* Wu2t = Wt + (size_t)(6 + l) * 16384;
        if (l < N_CONV - 1) {
            k_update<false><<<GA2, 256, 0, stream>>>((const u16*)agg16, bu1 + l * 128,
                                                     bu2 + l * 128, Wu1t, Wu2t,
                                                     Wt + (size_t)(l + 1) * 16384,
                                                     bn + (l + 1) * 128,
                                                     r_buf, (u16*)rf16, Wr2, br2, mol, out);
        } else {
            k_update<true><<<GA2, 256, 0, stream>>>((const u16*)agg16, bu1 + l * 128,
                                                    bu2 + l * 128, Wu1t, Wu2t,
                                                    Wt + (size_t)9 * 16384, br1,
                                                    r_buf, (u16*)rf16, Wr2, br2, mol, out);
        }
    }
}